// Round 1
// baseline (1325.393 us; speedup 1.0000x reference)
//
#include <hip/hip_runtime.h>

#define NODES 50000
#define EDGES 800000
#define FIN 128
#define DIM 256
#define GRAPHS 256

__global__ void degree_kernel(const int* __restrict__ src, const int* __restrict__ dst,
                              int* __restrict__ deg_out, int* __restrict__ deg_in, int e) {
    int i = blockIdx.x * blockDim.x + threadIdx.x;
    if (i < e) {
        atomicAdd(&deg_out[src[i]], 1);
        atomicAdd(&deg_in[dst[i]], 1);
    }
}

__global__ void norm_kernel(const int* __restrict__ deg_out, const int* __restrict__ deg_in,
                            float* __restrict__ out_norm, float* __restrict__ in_norm, int n) {
    int i = blockIdx.x * blockDim.x + threadIdx.x;
    if (i < n) {
        out_norm[i] = rsqrtf(fmaxf((float)deg_out[i], 1.0f));
        in_norm[i]  = rsqrtf(fmaxf((float)deg_in[i], 1.0f));
    }
}

// Single-block exclusive scan of deg_in -> row_start[0..n], also seeds cursor.
__global__ __launch_bounds__(1024) void scan_kernel(const int* __restrict__ deg,
                                                    int* __restrict__ row_start,
                                                    int* __restrict__ cursor, int n) {
    __shared__ int sums[1024];
    int tid = threadIdx.x;
    int C = (n + 1023) >> 10;
    int b = tid * C;
    int e = min(b + C, n);
    int s = 0;
    for (int i = b; i < e; ++i) s += deg[i];
    sums[tid] = s;
    __syncthreads();
    for (int off = 1; off < 1024; off <<= 1) {
        int t = (tid >= off) ? sums[tid - off] : 0;
        __syncthreads();
        sums[tid] += t;
        __syncthreads();
    }
    int run = sums[tid] - s;   // exclusive prefix of this thread's chunk
    for (int i = b; i < e; ++i) {
        row_start[i] = run;
        cursor[i] = run;
        run += deg[i];
    }
    if (tid == 1023) row_start[n] = run;  // thread 1023's chunk is empty; run == total
}

__global__ void scatter_kernel(const int* __restrict__ src, const int* __restrict__ dst,
                               int* __restrict__ cursor, int* __restrict__ src_sorted, int e) {
    int i = blockIdx.x * blockDim.x + threadIdx.x;
    if (i < e) {
        int d = dst[i];
        int pos = atomicAdd(&cursor[d], 1);
        src_sorted[pos] = src[i];
    }
}

// One block per dst node, D threads (one feature each). No atomics.
template<int D>
__global__ void aggregate_kernel(const float* __restrict__ h, const int* __restrict__ row_start,
                                 const int* __restrict__ src_sorted,
                                 const float* __restrict__ out_norm,
                                 const float* __restrict__ in_norm, float* __restrict__ out) {
    int node = blockIdx.x;
    int f = threadIdx.x;
    int e0 = row_start[node], e1 = row_start[node + 1];
    float acc = 0.0f;
    for (int e = e0; e < e1; ++e) {
        int s = src_sorted[e];
        acc += h[(size_t)s * D + f] * out_norm[s];
    }
    out[(size_t)node * D + f] = acc * in_norm[node];
}

// fp32 tiled GEMM: C[M,N] = A[M,K] @ W[K,N] + bias, optional relu.
// BM=BN=64, BK=16, 256 threads, 4x4 microtile.
__global__ __launch_bounds__(256) void gemm_bias_kernel(const float* __restrict__ A,
                                                        const float* __restrict__ W,
                                                        const float* __restrict__ bias,
                                                        float* __restrict__ C,
                                                        int M, int K, int N, int relu) {
    __shared__ float As[16][68];   // [k][m], padded stride 68 (272B, 16B-aligned rows)
    __shared__ float Bs[16][68];   // [k][n]
    int tid = threadIdx.x;
    int tx = tid & 15, ty = tid >> 4;
    int bm = blockIdx.x * 64, bn = blockIdx.y * 64;
    float acc[4][4] = {};
    int ar = tid >> 2, ac4 = (tid & 3) << 2;     // A tile: 64 rows x 16 k
    int bk = tid >> 4, bn4 = (tid & 15) << 2;    // B tile: 16 k x 64 n
    for (int k0 = 0; k0 < K; k0 += 16) {
        float4 a = make_float4(0.f, 0.f, 0.f, 0.f);
        if (bm + ar < M) a = *(const float4*)&A[(size_t)(bm + ar) * K + k0 + ac4];
        As[ac4 + 0][ar] = a.x;
        As[ac4 + 1][ar] = a.y;
        As[ac4 + 2][ar] = a.z;
        As[ac4 + 3][ar] = a.w;
        *(float4*)&Bs[bk][bn4] = *(const float4*)&W[(size_t)(k0 + bk) * N + bn + bn4];
        __syncthreads();
#pragma unroll
        for (int kk = 0; kk < 16; ++kk) {
            float4 a4 = *(float4*)&As[kk][ty << 2];
            float4 b4 = *(float4*)&Bs[kk][tx << 2];
            float av[4] = {a4.x, a4.y, a4.z, a4.w};
            float bv[4] = {b4.x, b4.y, b4.z, b4.w};
#pragma unroll
            for (int i = 0; i < 4; ++i)
#pragma unroll
                for (int j = 0; j < 4; ++j)
                    acc[i][j] = fmaf(av[i], bv[j], acc[i][j]);
        }
        __syncthreads();
    }
#pragma unroll
    for (int i = 0; i < 4; ++i) {
        int row = bm + (ty << 2) + i;
        if (row >= M) continue;
        float4 v;
        float* vp = &v.x;
#pragma unroll
        for (int j = 0; j < 4; ++j) {
            float t = acc[i][j] + bias[bn + (tx << 2) + j];
            if (relu) t = fmaxf(t, 0.0f);
            vp[j] = t;
        }
        *(float4*)&C[(size_t)row * N + bn + (tx << 2)] = v;
    }
}

// Sum of per-row L2 norms of h [n, DIM]. One wave per row.
__global__ void rownorm_kernel(const float* __restrict__ h, float* __restrict__ norm_sum, int n) {
    int row = blockIdx.x * 4 + (threadIdx.x >> 6);
    int lane = threadIdx.x & 63;
    float s = 0.0f;
    if (row < n) {
        float4 v = *(const float4*)&h[(size_t)row * DIM + lane * 4];
        s = v.x * v.x + v.y * v.y + v.z * v.z + v.w * v.w;
    }
#pragma unroll
    for (int off = 32; off > 0; off >>= 1) s += __shfl_down(s, off);
    if (lane == 0 && row < n) atomicAdd(norm_sum, sqrtf(s));
}

__global__ void factor_kernel(const float* __restrict__ norm_sum, float* __restrict__ factor) {
    *factor = 16.0f * (float)NODES / *norm_sum;   // sqrt(256) / mean
}

__global__ void pool_kernel(const float* __restrict__ h, const int* __restrict__ n2g,
                            const float* __restrict__ factor, float* __restrict__ out) {
    int node = blockIdx.x;
    int f = threadIdx.x;
    float fac = *factor;
    float v = h[(size_t)node * DIM + f] * fac;
    atomicAdd(&out[(size_t)n2g[node] * DIM + f], v);
}

extern "C" void kernel_launch(void* const* d_in, const int* in_sizes, int n_in,
                              void* d_out, int out_size, void* d_ws, size_t ws_size,
                              hipStream_t stream) {
    const float* x  = (const float*)d_in[0];
    const float* W1 = (const float*)d_in[1];
    const float* b1 = (const float*)d_in[2];
    const float* W2 = (const float*)d_in[3];
    const float* b2 = (const float*)d_in[4];
    const int* src = (const int*)d_in[5];
    const int* dst = (const int*)d_in[6];
    const int* n2g = (const int*)d_in[7];
    float* out = (float*)d_out;

    char* ws = (char*)d_ws;
    size_t off = 0;
    auto alloc = [&](size_t bytes) {
        char* p = ws + off;
        off = (off + bytes + 255) & ~(size_t)255;
        return p;
    };
    int* deg_out    = (int*)alloc(NODES * 4);
    int* deg_in     = (int*)alloc(NODES * 4);
    float* out_norm = (float*)alloc(NODES * 4);
    float* in_norm  = (float*)alloc(NODES * 4);
    int* row_start  = (int*)alloc((NODES + 1) * 4);
    int* cursor     = (int*)alloc(NODES * 4);
    int* src_sorted = (int*)alloc(EDGES * 4);
    float* norm_sum = (float*)alloc(4);
    float* factor   = (float*)alloc(4);
    float* aggA     = (float*)alloc((size_t)NODES * DIM * 4);  // agg1 (128) then agg2 (256)
    float* hB       = (float*)alloc((size_t)NODES * DIM * 4);  // h1 then h2

    hipMemsetAsync(deg_out, 0, NODES * 4, stream);
    hipMemsetAsync(deg_in, 0, NODES * 4, stream);
    hipMemsetAsync(norm_sum, 0, 4, stream);
    hipMemsetAsync(d_out, 0, (size_t)out_size * 4, stream);

    degree_kernel<<<(EDGES + 255) / 256, 256, 0, stream>>>(src, dst, deg_out, deg_in, EDGES);
    norm_kernel<<<(NODES + 255) / 256, 256, 0, stream>>>(deg_out, deg_in, out_norm, in_norm, NODES);
    scan_kernel<<<1, 1024, 0, stream>>>(deg_in, row_start, cursor, NODES);
    scatter_kernel<<<(EDGES + 255) / 256, 256, 0, stream>>>(src, dst, cursor, src_sorted, EDGES);

    // Layer 1: aggregate x (128), GEMM -> relu(agg@W1+b1) [50000,256]
    aggregate_kernel<FIN><<<NODES, FIN, 0, stream>>>(x, row_start, src_sorted, out_norm, in_norm, aggA);
    dim3 g1((NODES + 63) / 64, DIM / 64);
    gemm_bias_kernel<<<g1, 256, 0, stream>>>(aggA, W1, b1, hB, NODES, FIN, DIM, 1);

    // Layer 2: aggregate h1 (256), GEMM -> agg@W2+b2
    aggregate_kernel<DIM><<<NODES, DIM, 0, stream>>>(hB, row_start, src_sorted, out_norm, in_norm, aggA);
    gemm_bias_kernel<<<g1, 256, 0, stream>>>(aggA, W2, b2, hB, NODES, DIM, DIM, 0);

    // Scale factor and sum-pool
    rownorm_kernel<<<(NODES + 3) / 4, 256, 0, stream>>>(hB, norm_sum, NODES);
    factor_kernel<<<1, 1, 0, stream>>>(norm_sum, factor);
    pool_kernel<<<NODES, DIM, 0, stream>>>(hB, n2g, factor, out);
}

// Round 2
// 719.788 us; speedup vs baseline: 1.8414x; 1.8414x over previous
//
#include <hip/hip_runtime.h>

#define NODES 50000
#define EDGES 800000
#define FIN 128
#define DIM 256
#define GRAPHS 256

__global__ void degree_kernel(const int* __restrict__ src, const int* __restrict__ dst,
                              int* __restrict__ deg_out, int* __restrict__ deg_in, int e) {
    int i = blockIdx.x * blockDim.x + threadIdx.x;
    if (i < e) {
        atomicAdd(&deg_out[src[i]], 1);
        atomicAdd(&deg_in[dst[i]], 1);
    }
}

__global__ void norm_kernel(const int* __restrict__ deg_out, const int* __restrict__ deg_in,
                            float* __restrict__ out_norm, float* __restrict__ in_norm, int n) {
    int i = blockIdx.x * blockDim.x + threadIdx.x;
    if (i < n) {
        out_norm[i] = rsqrtf(fmaxf((float)deg_out[i], 1.0f));
        in_norm[i]  = rsqrtf(fmaxf((float)deg_in[i], 1.0f));
    }
}

// Single-block exclusive scan of deg_in -> row_start[0..n], also seeds cursor.
__global__ __launch_bounds__(1024) void scan_kernel(const int* __restrict__ deg,
                                                    int* __restrict__ row_start,
                                                    int* __restrict__ cursor, int n) {
    __shared__ int sums[1024];
    int tid = threadIdx.x;
    int C = (n + 1023) >> 10;
    int b = tid * C;
    int e = min(b + C, n);
    int s = 0;
    for (int i = b; i < e; ++i) s += deg[i];
    sums[tid] = s;
    __syncthreads();
    for (int off = 1; off < 1024; off <<= 1) {
        int t = (tid >= off) ? sums[tid - off] : 0;
        __syncthreads();
        sums[tid] += t;
        __syncthreads();
    }
    int run = sums[tid] - s;   // exclusive prefix of this thread's chunk
    for (int i = b; i < e; ++i) {
        row_start[i] = run;
        cursor[i] = run;
        run += deg[i];
    }
    if (tid == 1023) row_start[n] = run;  // thread 1023's chunk is empty; run == total
}

__global__ void scatter_kernel(const int* __restrict__ src, const int* __restrict__ dst,
                               int* __restrict__ cursor, int* __restrict__ src_sorted, int e) {
    int i = blockIdx.x * blockDim.x + threadIdx.x;
    if (i < e) {
        int d = dst[i];
        int pos = atomicAdd(&cursor[d], 1);
        src_sorted[pos] = src[i];
    }
}

// One block per dst node, D threads (one feature each). No atomics.
template<int D>
__global__ void aggregate_kernel(const float* __restrict__ h, const int* __restrict__ row_start,
                                 const int* __restrict__ src_sorted,
                                 const float* __restrict__ out_norm,
                                 const float* __restrict__ in_norm, float* __restrict__ out) {
    int node = blockIdx.x;
    int f = threadIdx.x;
    int e0 = row_start[node], e1 = row_start[node + 1];
    float acc = 0.0f;
    for (int e = e0; e < e1; ++e) {
        int s = src_sorted[e];
        acc += h[(size_t)s * D + f] * out_norm[s];
    }
    out[(size_t)node * D + f] = acc * in_norm[node];
}

// fp32 tiled GEMM: C[M,N] = A[M,K] @ W[K,N] + bias, optional relu.
// BM=BN=64, BK=16, 256 threads, 4x4 microtile.
__global__ __launch_bounds__(256) void gemm_bias_kernel(const float* __restrict__ A,
                                                        const float* __restrict__ W,
                                                        const float* __restrict__ bias,
                                                        float* __restrict__ C,
                                                        int M, int K, int N, int relu) {
    __shared__ float As[16][68];   // [k][m], padded stride 68 (272B, 16B-aligned rows)
    __shared__ float Bs[16][68];   // [k][n]
    int tid = threadIdx.x;
    int tx = tid & 15, ty = tid >> 4;
    int bm = blockIdx.x * 64, bn = blockIdx.y * 64;
    float acc[4][4] = {};
    int ar = tid >> 2, ac4 = (tid & 3) << 2;     // A tile: 64 rows x 16 k
    int bk = tid >> 4, bn4 = (tid & 15) << 2;    // B tile: 16 k x 64 n
    for (int k0 = 0; k0 < K; k0 += 16) {
        float4 a = make_float4(0.f, 0.f, 0.f, 0.f);
        if (bm + ar < M) a = *(const float4*)&A[(size_t)(bm + ar) * K + k0 + ac4];
        As[ac4 + 0][ar] = a.x;
        As[ac4 + 1][ar] = a.y;
        As[ac4 + 2][ar] = a.z;
        As[ac4 + 3][ar] = a.w;
        *(float4*)&Bs[bk][bn4] = *(const float4*)&W[(size_t)(k0 + bk) * N + bn + bn4];
        __syncthreads();
#pragma unroll
        for (int kk = 0; kk < 16; ++kk) {
            float4 a4 = *(float4*)&As[kk][ty << 2];
            float4 b4 = *(float4*)&Bs[kk][tx << 2];
            float av[4] = {a4.x, a4.y, a4.z, a4.w};
            float bv[4] = {b4.x, b4.y, b4.z, b4.w};
#pragma unroll
            for (int i = 0; i < 4; ++i)
#pragma unroll
                for (int j = 0; j < 4; ++j)
                    acc[i][j] = fmaf(av[i], bv[j], acc[i][j]);
        }
        __syncthreads();
    }
#pragma unroll
    for (int i = 0; i < 4; ++i) {
        int row = bm + (ty << 2) + i;
        if (row >= M) continue;
        float4 v;
        float* vp = &v.x;
#pragma unroll
        for (int j = 0; j < 4; ++j) {
            float t = acc[i][j] + bias[bn + (tx << 2) + j];
            if (relu) t = fmaxf(t, 0.0f);
            vp[j] = t;
        }
        *(float4*)&C[(size_t)row * N + bn + (tx << 2)] = v;
    }
}

// Sum of per-row L2 norms of h [n, DIM].
// 256 blocks x 4 waves, grid-stride over rows; one atomicAdd per BLOCK (256 total,
// was 50000 same-address atomics = 635 us of pure serialization).
__global__ __launch_bounds__(256) void rownorm_kernel(const float* __restrict__ h,
                                                      float* __restrict__ norm_sum, int n) {
    __shared__ float wsum[4];
    int wave = threadIdx.x >> 6;
    int lane = threadIdx.x & 63;
    int gwave = blockIdx.x * 4 + wave;
    int nwaves = gridDim.x * 4;
    float local = 0.0f;
    for (int row = gwave; row < n; row += nwaves) {
        float4 v = *(const float4*)&h[(size_t)row * DIM + lane * 4];
        float s = v.x * v.x + v.y * v.y + v.z * v.z + v.w * v.w;
#pragma unroll
        for (int off = 32; off > 0; off >>= 1) s += __shfl_down(s, off);
        if (lane == 0) local += sqrtf(s);
    }
    if (lane == 0) wsum[wave] = local;
    __syncthreads();
    if (threadIdx.x == 0) {
        float t = wsum[0] + wsum[1] + wsum[2] + wsum[3];
        atomicAdd(norm_sum, t);
    }
}

__global__ void factor_kernel(const float* __restrict__ norm_sum, float* __restrict__ factor) {
    *factor = 16.0f * (float)NODES / *norm_sum;   // sqrt(256) / mean
}

__global__ void pool_kernel(const float* __restrict__ h, const int* __restrict__ n2g,
                            const float* __restrict__ factor, float* __restrict__ out) {
    int node = blockIdx.x;
    int f = threadIdx.x;
    float fac = *factor;
    float v = h[(size_t)node * DIM + f] * fac;
    atomicAdd(&out[(size_t)n2g[node] * DIM + f], v);
}

extern "C" void kernel_launch(void* const* d_in, const int* in_sizes, int n_in,
                              void* d_out, int out_size, void* d_ws, size_t ws_size,
                              hipStream_t stream) {
    const float* x  = (const float*)d_in[0];
    const float* W1 = (const float*)d_in[1];
    const float* b1 = (const float*)d_in[2];
    const float* W2 = (const float*)d_in[3];
    const float* b2 = (const float*)d_in[4];
    const int* src = (const int*)d_in[5];
    const int* dst = (const int*)d_in[6];
    const int* n2g = (const int*)d_in[7];
    float* out = (float*)d_out;

    char* ws = (char*)d_ws;
    size_t off = 0;
    auto alloc = [&](size_t bytes) {
        char* p = ws + off;
        off = (off + bytes + 255) & ~(size_t)255;
        return p;
    };
    int* deg_out    = (int*)alloc(NODES * 4);
    int* deg_in     = (int*)alloc(NODES * 4);
    float* out_norm = (float*)alloc(NODES * 4);
    float* in_norm  = (float*)alloc(NODES * 4);
    int* row_start  = (int*)alloc((NODES + 1) * 4);
    int* cursor     = (int*)alloc(NODES * 4);
    int* src_sorted = (int*)alloc(EDGES * 4);
    float* norm_sum = (float*)alloc(4);
    float* factor   = (float*)alloc(4);
    float* aggA     = (float*)alloc((size_t)NODES * DIM * 4);  // agg1 (128) then agg2 (256)
    float* hB       = (float*)alloc((size_t)NODES * DIM * 4);  // h1 then h2

    hipMemsetAsync(deg_out, 0, NODES * 4, stream);
    hipMemsetAsync(deg_in, 0, NODES * 4, stream);
    hipMemsetAsync(norm_sum, 0, 4, stream);
    hipMemsetAsync(d_out, 0, (size_t)out_size * 4, stream);

    degree_kernel<<<(EDGES + 255) / 256, 256, 0, stream>>>(src, dst, deg_out, deg_in, EDGES);
    norm_kernel<<<(NODES + 255) / 256, 256, 0, stream>>>(deg_out, deg_in, out_norm, in_norm, NODES);
    scan_kernel<<<1, 1024, 0, stream>>>(deg_in, row_start, cursor, NODES);
    scatter_kernel<<<(EDGES + 255) / 256, 256, 0, stream>>>(src, dst, cursor, src_sorted, EDGES);

    // Layer 1: aggregate x (128), GEMM -> relu(agg@W1+b1) [50000,256]
    aggregate_kernel<FIN><<<NODES, FIN, 0, stream>>>(x, row_start, src_sorted, out_norm, in_norm, aggA);
    dim3 g1((NODES + 63) / 64, DIM / 64);
    gemm_bias_kernel<<<g1, 256, 0, stream>>>(aggA, W1, b1, hB, NODES, FIN, DIM, 1);

    // Layer 2: aggregate h1 (256), GEMM -> agg@W2+b2
    aggregate_kernel<DIM><<<NODES, DIM, 0, stream>>>(hB, row_start, src_sorted, out_norm, in_norm, aggA);
    gemm_bias_kernel<<<g1, 256, 0, stream>>>(aggA, W2, b2, hB, NODES, DIM, DIM, 0);

    // Scale factor and sum-pool
    rownorm_kernel<<<256, 256, 0, stream>>>(hB, norm_sum, NODES);
    factor_kernel<<<1, 1, 0, stream>>>(norm_sum, factor);
    pool_kernel<<<NODES, DIM, 0, stream>>>(hB, n2g, factor, out);
}

// Round 3
// 527.693 us; speedup vs baseline: 2.5117x; 1.3640x over previous
//
#include <hip/hip_runtime.h>

#define NODES 50000
#define EDGES 800000
#define FIN 128
#define DIM 256
#define GRAPHS 256
#define PAD_M 50048   // 782 * 64

typedef short short8 __attribute__((ext_vector_type(8)));
typedef float f32x4 __attribute__((ext_vector_type(4)));

__device__ __forceinline__ float bf2f(uint u) { return __uint_as_float(u << 16); }
__device__ __forceinline__ ushort f2bf(float f) {
    uint b = __float_as_uint(f);
    return (ushort)((b + 0x7FFF + ((b >> 16) & 1)) >> 16);
}

__global__ void degree_kernel(const int* __restrict__ src, const int* __restrict__ dst,
                              int* __restrict__ deg_out, int* __restrict__ deg_in, int e) {
    int i = blockIdx.x * blockDim.x + threadIdx.x;
    if (i < e) {
        atomicAdd(&deg_out[src[i]], 1);
        atomicAdd(&deg_in[dst[i]], 1);
    }
}

__global__ void norm_kernel(const int* __restrict__ deg_out, const int* __restrict__ deg_in,
                            float* __restrict__ out_norm, float* __restrict__ in_norm, int n) {
    int i = blockIdx.x * blockDim.x + threadIdx.x;
    if (i < n) {
        out_norm[i] = rsqrtf(fmaxf((float)deg_out[i], 1.0f));
        in_norm[i]  = rsqrtf(fmaxf((float)deg_in[i], 1.0f));
    }
}

// Single-block exclusive scan of deg_in -> row_start[0..n], also seeds cursor.
__global__ __launch_bounds__(1024) void scan_kernel(const int* __restrict__ deg,
                                                    int* __restrict__ row_start,
                                                    int* __restrict__ cursor, int n) {
    __shared__ int sums[1024];
    int tid = threadIdx.x;
    int C = (n + 1023) >> 10;
    int b = tid * C;
    int e = min(b + C, n);
    int s = 0;
    for (int i = b; i < e; ++i) s += deg[i];
    sums[tid] = s;
    __syncthreads();
    for (int off = 1; off < 1024; off <<= 1) {
        int t = (tid >= off) ? sums[tid - off] : 0;
        __syncthreads();
        sums[tid] += t;
        __syncthreads();
    }
    int run = sums[tid] - s;
    for (int i = b; i < e; ++i) {
        row_start[i] = run;
        cursor[i] = run;
        run += deg[i];
    }
    if (tid == 1023) row_start[n] = run;
}

__global__ void scatter_kernel(const int* __restrict__ src, const int* __restrict__ dst,
                               int* __restrict__ cursor, int* __restrict__ src_sorted, int e) {
    int i = blockIdx.x * blockDim.x + threadIdx.x;
    if (i < e) {
        int d = dst[i];
        int pos = atomicAdd(&cursor[d], 1);
        src_sorted[pos] = src[i];
    }
}

// xs[i][f] = bf16(x[i][f] * out_norm[i]) — fused pre-scale + cast, float4/thread.
__global__ void prescale_x_kernel(const float* __restrict__ x, const float* __restrict__ out_norm,
                                  ushort* __restrict__ xs) {
    int t = blockIdx.x * blockDim.x + threadIdx.x;
    if (t >= NODES * FIN / 4) return;
    int row = t >> 5;  // FIN/4 = 32
    float on = out_norm[row];
    float4 v = ((const float4*)x)[t];
    ushort4 o;
    o.x = f2bf(v.x * on); o.y = f2bf(v.y * on);
    o.z = f2bf(v.z * on); o.w = f2bf(v.w * on);
    ((ushort4*)xs)[t] = o;
}

// WT[n][k] = bf16(W[k][n]) — tiny one-shot transpose+cast.
template<int K>
__global__ void castW_kernel(const float* __restrict__ W, ushort* __restrict__ WT) {
    int t = blockIdx.x * blockDim.x + threadIdx.x;
    if (t >= K * DIM) return;
    int n = t / K, k = t % K;
    WT[t] = f2bf(W[(size_t)k * DIM + n]);
}

// Gather-sum aggregation, bf16 in/out, fp32 accumulate. One wave per node.
// in rows are pre-scaled by out_norm; multiply by in_norm at the end.
template<int D>
__global__ __launch_bounds__(256) void agg_kernel(const ushort* __restrict__ in,
                                                  const int* __restrict__ row_start,
                                                  const int* __restrict__ src_sorted,
                                                  const float* __restrict__ in_norm,
                                                  ushort* __restrict__ out) {
    constexpr int VPL = D / 64;       // bf16 per lane (2 or 4)
    constexpr int NU = VPL / 2;       // uint loads per lane
    int wave = threadIdx.x >> 6, lane = threadIdx.x & 63;
    int node = blockIdx.x * 4 + wave;
    if (node >= NODES) return;
    int off = lane * VPL;
    int e0 = row_start[node], e1 = row_start[node + 1];
    float acc[VPL] = {};
    int e = e0;
    for (; e + 1 < e1; e += 2) {
        int s0 = src_sorted[e], s1 = src_sorted[e + 1];
        const uint* p0 = (const uint*)(in + (size_t)s0 * D + off);
        const uint* p1 = (const uint*)(in + (size_t)s1 * D + off);
        uint u0[NU], u1[NU];
#pragma unroll
        for (int q = 0; q < NU; ++q) { u0[q] = p0[q]; u1[q] = p1[q]; }
#pragma unroll
        for (int q = 0; q < NU; ++q) {
            acc[2*q]   += bf2f(u0[q] & 0xFFFFu) + bf2f(u1[q] & 0xFFFFu);
            acc[2*q+1] += bf2f(u0[q] >> 16)     + bf2f(u1[q] >> 16);
        }
    }
    if (e < e1) {
        int s0 = src_sorted[e];
        const uint* p0 = (const uint*)(in + (size_t)s0 * D + off);
#pragma unroll
        for (int q = 0; q < NU; ++q) {
            uint u = p0[q];
            acc[2*q]   += bf2f(u & 0xFFFFu);
            acc[2*q+1] += bf2f(u >> 16);
        }
    }
    float inn = in_norm[node];
    uint* po = (uint*)(out + (size_t)node * D + off);
#pragma unroll
    for (int q = 0; q < NU; ++q) {
        uint lo = f2bf(acc[2*q] * inn);
        uint hi = f2bf(acc[2*q+1] * inn);
        po[q] = lo | (hi << 16);
    }
}

// MFMA GEMM: C[M,256] = A[M,K](bf16) @ W[K,256] + bias.
// A row-major bf16, W given transposed WT[256][K] bf16.
// Block: 64 rows x 256 cols, 4 waves (wave w -> cols w*64..w*64+63), no LDS.
// MODE 0: out bf16 = relu(acc+bias)*scale[row]   (h1s, pre-scaled for next gather)
// MODE 1: out f32  = acc+bias                    (h2)
template<int K, int MODE>
__global__ __launch_bounds__(256) void gemm_mfma_kernel(const ushort* __restrict__ A,
                                                        const ushort* __restrict__ WT,
                                                        const float* __restrict__ bias,
                                                        void* __restrict__ Cout,
                                                        const float* __restrict__ scale,
                                                        int M) {
    int lane = threadIdx.x & 63, wave = threadIdx.x >> 6;
    int m0 = blockIdx.x * 64, n0 = wave * 64;
    int ll = lane & 15, lh = lane >> 4;
    f32x4 acc[4][4] = {};
    const ushort* Ab = A  + (size_t)(m0 + ll) * K + lh * 8;
    const ushort* Bb = WT + (size_t)(n0 + ll) * K + lh * 8;
#pragma unroll
    for (int k0 = 0; k0 < K; k0 += 32) {
        short8 a[4], b[4];
#pragma unroll
        for (int mi = 0; mi < 4; ++mi) a[mi] = *(const short8*)(Ab + (size_t)mi * 16 * K + k0);
#pragma unroll
        for (int ni = 0; ni < 4; ++ni) b[ni] = *(const short8*)(Bb + (size_t)ni * 16 * K + k0);
#pragma unroll
        for (int mi = 0; mi < 4; ++mi)
#pragma unroll
            for (int ni = 0; ni < 4; ++ni)
                acc[mi][ni] = __builtin_amdgcn_mfma_f32_16x16x32_bf16(a[mi], b[ni], acc[mi][ni], 0, 0, 0);
    }
#pragma unroll
    for (int mi = 0; mi < 4; ++mi) {
#pragma unroll
        for (int r = 0; r < 4; ++r) {
            int row = m0 + mi * 16 + lh * 4 + r;
            if (row >= M) continue;
            float sc = (MODE == 0) ? scale[row] : 1.0f;
#pragma unroll
            for (int ni = 0; ni < 4; ++ni) {
                int col = n0 + ni * 16 + ll;
                float v = acc[mi][ni][r] + bias[col];
                if (MODE == 0) {
                    v = fmaxf(v, 0.0f) * sc;
                    ((ushort*)Cout)[(size_t)row * DIM + col] = f2bf(v);
                } else {
                    ((float*)Cout)[(size_t)row * DIM + col] = v;
                }
            }
        }
    }
}

// Sum of per-row L2 norms of h [n, DIM]. 256 blocks, one atomic per block.
__global__ __launch_bounds__(256) void rownorm_kernel(const float* __restrict__ h,
                                                      float* __restrict__ norm_sum, int n) {
    __shared__ float wsum[4];
    int wave = threadIdx.x >> 6;
    int lane = threadIdx.x & 63;
    int gwave = blockIdx.x * 4 + wave;
    int nwaves = gridDim.x * 4;
    float local = 0.0f;
    for (int row = gwave; row < n; row += nwaves) {
        float4 v = *(const float4*)&h[(size_t)row * DIM + lane * 4];
        float s = v.x * v.x + v.y * v.y + v.z * v.z + v.w * v.w;
#pragma unroll
        for (int off = 32; off > 0; off >>= 1) s += __shfl_down(s, off);
        if (lane == 0) local += sqrtf(s);
    }
    if (lane == 0) wsum[wave] = local;
    __syncthreads();
    if (threadIdx.x == 0) {
        float t = wsum[0] + wsum[1] + wsum[2] + wsum[3];
        atomicAdd(norm_sum, t);
    }
}

__global__ void factor_kernel(const float* __restrict__ norm_sum, float* __restrict__ factor) {
    *factor = 16.0f * (float)NODES / *norm_sum;   // sqrt(256) / mean
}

__global__ void pool_kernel(const float* __restrict__ h, const int* __restrict__ n2g,
                            const float* __restrict__ factor, float* __restrict__ out) {
    int node = blockIdx.x;
    int f = threadIdx.x;
    float fac = *factor;
    float v = h[(size_t)node * DIM + f] * fac;
    atomicAdd(&out[(size_t)n2g[node] * DIM + f], v);
}

extern "C" void kernel_launch(void* const* d_in, const int* in_sizes, int n_in,
                              void* d_out, int out_size, void* d_ws, size_t ws_size,
                              hipStream_t stream) {
    const float* x  = (const float*)d_in[0];
    const float* W1 = (const float*)d_in[1];
    const float* b1 = (const float*)d_in[2];
    const float* W2 = (const float*)d_in[3];
    const float* b2 = (const float*)d_in[4];
    const int* src = (const int*)d_in[5];
    const int* dst = (const int*)d_in[6];
    const int* n2g = (const int*)d_in[7];
    float* out = (float*)d_out;

    char* ws = (char*)d_ws;
    size_t off = 0;
    auto alloc = [&](size_t bytes) {
        char* p = ws + off;
        off = (off + bytes + 255) & ~(size_t)255;
        return p;
    };
    int* deg_out    = (int*)alloc(NODES * 4);
    int* deg_in     = (int*)alloc(NODES * 4);
    float* out_norm = (float*)alloc(NODES * 4);
    float* in_norm  = (float*)alloc(NODES * 4);
    int* row_start  = (int*)alloc((NODES + 1) * 4);
    int* cursor     = (int*)alloc(NODES * 4);
    int* src_sorted = (int*)alloc(EDGES * 4);
    float* norm_sum = (float*)alloc(4);
    float* factor   = (float*)alloc(4);
    ushort* W1T     = (ushort*)alloc((size_t)DIM * FIN * 2);   // [256][128]
    ushort* W2T     = (ushort*)alloc((size_t)DIM * DIM * 2);   // [256][256]
    // Aliased feature regions:
    // P0 (12.8MB): xs [PAD_M][128] bf16   -> later low half of A2
    // P1 (12.8MB): A1 [PAD_M][128] bf16   -> later high half of A2
    // H  (25.6MB): h1s [PAD_M][256] bf16  -> later low half of h2
    // Q  (25.6MB): high half of h2 [PAD_M][256] f32
    ushort* xs  = (ushort*)alloc((size_t)PAD_M * FIN * 2);
    ushort* A1  = (ushort*)alloc((size_t)PAD_M * FIN * 2);
    ushort* h1s = (ushort*)alloc((size_t)PAD_M * DIM * 2);
    alloc((size_t)PAD_M * DIM * 2);  // Q
    ushort* A2 = xs;                  // [PAD_M][256] bf16, overlays P0+P1
    float*  h2 = (float*)h1s;         // [PAD_M][256] f32, overlays H+Q

    hipMemsetAsync(deg_out, 0, NODES * 4, stream);
    hipMemsetAsync(deg_in, 0, NODES * 4, stream);
    hipMemsetAsync(norm_sum, 0, 4, stream);
    hipMemsetAsync(d_out, 0, (size_t)out_size * 4, stream);

    degree_kernel<<<(EDGES + 255) / 256, 256, 0, stream>>>(src, dst, deg_out, deg_in, EDGES);
    norm_kernel<<<(NODES + 255) / 256, 256, 0, stream>>>(deg_out, deg_in, out_norm, in_norm, NODES);
    scan_kernel<<<1, 1024, 0, stream>>>(deg_in, row_start, cursor, NODES);
    scatter_kernel<<<(EDGES + 255) / 256, 256, 0, stream>>>(src, dst, cursor, src_sorted, EDGES);

    prescale_x_kernel<<<(NODES * FIN / 4 + 255) / 256, 256, 0, stream>>>(x, out_norm, xs);
    castW_kernel<FIN><<<(FIN * DIM + 255) / 256, 256, 0, stream>>>(W1, W1T);
    castW_kernel<DIM><<<(DIM * DIM + 255) / 256, 256, 0, stream>>>(W2, W2T);

    // Layer 1
    agg_kernel<FIN><<<(NODES + 3) / 4, 256, 0, stream>>>(xs, row_start, src_sorted, in_norm, A1);
    gemm_mfma_kernel<FIN, 0><<<PAD_M / 64, 256, 0, stream>>>(A1, W1T, b1, h1s, out_norm, NODES);

    // Layer 2
    agg_kernel<DIM><<<(NODES + 3) / 4, 256, 0, stream>>>(h1s, row_start, src_sorted, in_norm, A2);
    gemm_mfma_kernel<DIM, 1><<<PAD_M / 64, 256, 0, stream>>>(A2, W2T, b2, h2, nullptr, NODES);

    // Scale factor and sum-pool
    rownorm_kernel<<<256, 256, 0, stream>>>(h2, norm_sum, NODES);
    factor_kernel<<<1, 1, 0, stream>>>(norm_sum, factor);
    pool_kernel<<<NODES, DIM, 0, stream>>>(h2, n2g, factor, out);
}

// Round 4
// 419.283 us; speedup vs baseline: 3.1611x; 1.2586x over previous
//
#include <hip/hip_runtime.h>

#define NODES 50000
#define EDGES 800000
#define FIN 128
#define DIM 256
#define GRAPHS 256
#define PAD_M 50048   // 782 * 64
#define SCAN_BLOCKS ((NODES + 255) / 256)   // 196

typedef short short8 __attribute__((ext_vector_type(8)));
typedef float f32x4 __attribute__((ext_vector_type(4)));

__device__ __forceinline__ float bf2f(uint u) { return __uint_as_float(u << 16); }
__device__ __forceinline__ ushort f2bf(float f) {
    uint b = __float_as_uint(f);
    return (ushort)((b + 0x7FFF + ((b >> 16) & 1)) >> 16);
}

__global__ void degree_kernel(const int* __restrict__ src, const int* __restrict__ dst,
                              int* __restrict__ deg_out, int* __restrict__ deg_in, int e) {
    int i = blockIdx.x * blockDim.x + threadIdx.x;
    if (i < e) {
        atomicAdd(&deg_out[src[i]], 1);
        atomicAdd(&deg_in[dst[i]], 1);
    }
}

__global__ void norm_kernel(const int* __restrict__ deg_out, const int* __restrict__ deg_in,
                            float* __restrict__ out_norm, float* __restrict__ in_norm, int n) {
    int i = blockIdx.x * blockDim.x + threadIdx.x;
    if (i < n) {
        out_norm[i] = rsqrtf(fmaxf((float)deg_out[i], 1.0f));
        in_norm[i]  = rsqrtf(fmaxf((float)deg_in[i], 1.0f));
    }
}

// ---- 3-phase multi-block exclusive scan of deg -> row_start[0..n] + cursor ----
// Phase 1: per-block (256-elem chunk) sums.
__global__ __launch_bounds__(256) void scan_partials(const int* __restrict__ deg,
                                                     int* __restrict__ block_sums, int n) {
    __shared__ int red[4];
    int i = blockIdx.x * 256 + threadIdx.x;
    int v = (i < n) ? deg[i] : 0;
    int wave = threadIdx.x >> 6, lane = threadIdx.x & 63;
#pragma unroll
    for (int off = 32; off > 0; off >>= 1) v += __shfl_down(v, off);
    if (lane == 0) red[wave] = v;
    __syncthreads();
    if (threadIdx.x == 0) block_sums[blockIdx.x] = red[0] + red[1] + red[2] + red[3];
}

// Phase 2: single small block scans the block sums (nb <= 256), writes row_start[n]=total.
__global__ __launch_bounds__(256) void scan_blocksums(int* __restrict__ block_sums,
                                                      int* __restrict__ row_start, int nb, int n) {
    __shared__ int s[256];
    int t = threadIdx.x;
    int v = (t < nb) ? block_sums[t] : 0;
    s[t] = v;
    __syncthreads();
#pragma unroll
    for (int off = 1; off < 256; off <<= 1) {
        int u = (t >= off) ? s[t - off] : 0;
        __syncthreads();
        s[t] += u;
        __syncthreads();
    }
    if (t < nb) block_sums[t] = s[t] - v;          // exclusive prefix
    if (t == nb - 1) row_start[n] = s[t];          // total
}

// Phase 3: intra-block exclusive scan + block offset -> row_start, cursor.
__global__ __launch_bounds__(256) void scan_final(const int* __restrict__ deg,
                                                  const int* __restrict__ block_sums,
                                                  int* __restrict__ row_start,
                                                  int* __restrict__ cursor, int n) {
    __shared__ int s[256];
    int t = threadIdx.x;
    int i = blockIdx.x * 256 + t;
    int v = (i < n) ? deg[i] : 0;
    s[t] = v;
    __syncthreads();
#pragma unroll
    for (int off = 1; off < 256; off <<= 1) {
        int u = (t >= off) ? s[t - off] : 0;
        __syncthreads();
        s[t] += u;
        __syncthreads();
    }
    if (i < n) {
        int excl = block_sums[blockIdx.x] + s[t] - v;
        row_start[i] = excl;
        cursor[i] = excl;
    }
}

__global__ void scatter_kernel(const int* __restrict__ src, const int* __restrict__ dst,
                               int* __restrict__ cursor, int* __restrict__ src_sorted, int e) {
    int i = blockIdx.x * blockDim.x + threadIdx.x;
    if (i < e) {
        int d = dst[i];
        int pos = atomicAdd(&cursor[d], 1);
        src_sorted[pos] = src[i];
    }
}

// xs[i][f] = bf16(x[i][f] * out_norm[i]) — fused pre-scale + cast, float4/thread.
__global__ void prescale_x_kernel(const float* __restrict__ x, const float* __restrict__ out_norm,
                                  ushort* __restrict__ xs) {
    int t = blockIdx.x * blockDim.x + threadIdx.x;
    if (t >= NODES * FIN / 4) return;
    int row = t >> 5;  // FIN/4 = 32
    float on = out_norm[row];
    float4 v = ((const float4*)x)[t];
    ushort4 o;
    o.x = f2bf(v.x * on); o.y = f2bf(v.y * on);
    o.z = f2bf(v.z * on); o.w = f2bf(v.w * on);
    ((ushort4*)xs)[t] = o;
}

// WT[n][k] = bf16(W[k][n]) — tiny one-shot transpose+cast.
template<int K>
__global__ void castW_kernel(const float* __restrict__ W, ushort* __restrict__ WT) {
    int t = blockIdx.x * blockDim.x + threadIdx.x;
    if (t >= K * DIM) return;
    int n = t / K, k = t % K;
    WT[t] = f2bf(W[(size_t)k * DIM + n]);
}

// Gather-sum aggregation, bf16 in/out, fp32 accumulate. One wave per node.
// in rows are pre-scaled by out_norm; multiply by in_norm at the end.
template<int D>
__global__ __launch_bounds__(256) void agg_kernel(const ushort* __restrict__ in,
                                                  const int* __restrict__ row_start,
                                                  const int* __restrict__ src_sorted,
                                                  const float* __restrict__ in_norm,
                                                  ushort* __restrict__ out) {
    constexpr int VPL = D / 64;       // bf16 per lane (2 or 4)
    constexpr int NU = VPL / 2;       // uint loads per lane
    int wave = threadIdx.x >> 6, lane = threadIdx.x & 63;
    int node = blockIdx.x * 4 + wave;
    if (node >= NODES) return;
    int off = lane * VPL;
    int e0 = row_start[node], e1 = row_start[node + 1];
    float acc[VPL] = {};
    int e = e0;
    for (; e + 1 < e1; e += 2) {
        int s0 = src_sorted[e], s1 = src_sorted[e + 1];
        const uint* p0 = (const uint*)(in + (size_t)s0 * D + off);
        const uint* p1 = (const uint*)(in + (size_t)s1 * D + off);
        uint u0[NU], u1[NU];
#pragma unroll
        for (int q = 0; q < NU; ++q) { u0[q] = p0[q]; u1[q] = p1[q]; }
#pragma unroll
        for (int q = 0; q < NU; ++q) {
            acc[2*q]   += bf2f(u0[q] & 0xFFFFu) + bf2f(u1[q] & 0xFFFFu);
            acc[2*q+1] += bf2f(u0[q] >> 16)     + bf2f(u1[q] >> 16);
        }
    }
    if (e < e1) {
        int s0 = src_sorted[e];
        const uint* p0 = (const uint*)(in + (size_t)s0 * D + off);
#pragma unroll
        for (int q = 0; q < NU; ++q) {
            uint u = p0[q];
            acc[2*q]   += bf2f(u & 0xFFFFu);
            acc[2*q+1] += bf2f(u >> 16);
        }
    }
    float inn = in_norm[node];
    uint* po = (uint*)(out + (size_t)node * D + off);
#pragma unroll
    for (int q = 0; q < NU; ++q) {
        uint lo = f2bf(acc[2*q] * inn);
        uint hi = f2bf(acc[2*q+1] * inn);
        po[q] = lo | (hi << 16);
    }
}

// MFMA GEMM: C[M,256] = A[M,K](bf16) @ W[K,256] + bias.
// A row-major bf16, W given transposed WT[256][K] bf16.
// Block: 64 rows x 256 cols, 4 waves (wave w -> cols w*64..w*64+63), no LDS.
// MODE 0: out bf16 = relu(acc+bias)*scale[row]   (h1s, pre-scaled for next gather)
// MODE 1: out f32  = acc+bias                    (h2)
template<int K, int MODE>
__global__ __launch_bounds__(256) void gemm_mfma_kernel(const ushort* __restrict__ A,
                                                        const ushort* __restrict__ WT,
                                                        const float* __restrict__ bias,
                                                        void* __restrict__ Cout,
                                                        const float* __restrict__ scale,
                                                        int M) {
    int lane = threadIdx.x & 63, wave = threadIdx.x >> 6;
    int m0 = blockIdx.x * 64, n0 = wave * 64;
    int ll = lane & 15, lh = lane >> 4;
    f32x4 acc[4][4] = {};
    const ushort* Ab = A  + (size_t)(m0 + ll) * K + lh * 8;
    const ushort* Bb = WT + (size_t)(n0 + ll) * K + lh * 8;
#pragma unroll
    for (int k0 = 0; k0 < K; k0 += 32) {
        short8 a[4], b[4];
#pragma unroll
        for (int mi = 0; mi < 4; ++mi) a[mi] = *(const short8*)(Ab + (size_t)mi * 16 * K + k0);
#pragma unroll
        for (int ni = 0; ni < 4; ++ni) b[ni] = *(const short8*)(Bb + (size_t)ni * 16 * K + k0);
#pragma unroll
        for (int mi = 0; mi < 4; ++mi)
#pragma unroll
            for (int ni = 0; ni < 4; ++ni)
                acc[mi][ni] = __builtin_amdgcn_mfma_f32_16x16x32_bf16(a[mi], b[ni], acc[mi][ni], 0, 0, 0);
    }
#pragma unroll
    for (int mi = 0; mi < 4; ++mi) {
#pragma unroll
        for (int r = 0; r < 4; ++r) {
            int row = m0 + mi * 16 + lh * 4 + r;
            if (row >= M) continue;
            float sc = (MODE == 0) ? scale[row] : 1.0f;
#pragma unroll
            for (int ni = 0; ni < 4; ++ni) {
                int col = n0 + ni * 16 + ll;
                float v = acc[mi][ni][r] + bias[col];
                if (MODE == 0) {
                    v = fmaxf(v, 0.0f) * sc;
                    ((ushort*)Cout)[(size_t)row * DIM + col] = f2bf(v);
                } else {
                    ((float*)Cout)[(size_t)row * DIM + col] = v;
                }
            }
        }
    }
}

// Sum of per-row L2 norms of h [n, DIM]. 256 blocks, one atomic per block.
__global__ __launch_bounds__(256) void rownorm_kernel(const float* __restrict__ h,
                                                      float* __restrict__ norm_sum, int n) {
    __shared__ float wsum[4];
    int wave = threadIdx.x >> 6;
    int lane = threadIdx.x & 63;
    int gwave = blockIdx.x * 4 + wave;
    int nwaves = gridDim.x * 4;
    float local = 0.0f;
    for (int row = gwave; row < n; row += nwaves) {
        float4 v = *(const float4*)&h[(size_t)row * DIM + lane * 4];
        float s = v.x * v.x + v.y * v.y + v.z * v.z + v.w * v.w;
#pragma unroll
        for (int off = 32; off > 0; off >>= 1) s += __shfl_down(s, off);
        if (lane == 0) local += sqrtf(s);
    }
    if (lane == 0) wsum[wave] = local;
    __syncthreads();
    if (threadIdx.x == 0) {
        float t = wsum[0] + wsum[1] + wsum[2] + wsum[3];
        atomicAdd(norm_sum, t);
    }
}

__global__ void factor_kernel(const float* __restrict__ norm_sum, float* __restrict__ factor) {
    *factor = 16.0f * (float)NODES / *norm_sum;   // sqrt(256) / mean
}

__global__ void pool_kernel(const float* __restrict__ h, const int* __restrict__ n2g,
                            const float* __restrict__ factor, float* __restrict__ out) {
    int node = blockIdx.x;
    int f = threadIdx.x;
    float fac = *factor;
    float v = h[(size_t)node * DIM + f] * fac;
    atomicAdd(&out[(size_t)n2g[node] * DIM + f], v);
}

extern "C" void kernel_launch(void* const* d_in, const int* in_sizes, int n_in,
                              void* d_out, int out_size, void* d_ws, size_t ws_size,
                              hipStream_t stream) {
    const float* x  = (const float*)d_in[0];
    const float* W1 = (const float*)d_in[1];
    const float* b1 = (const float*)d_in[2];
    const float* W2 = (const float*)d_in[3];
    const float* b2 = (const float*)d_in[4];
    const int* src = (const int*)d_in[5];
    const int* dst = (const int*)d_in[6];
    const int* n2g = (const int*)d_in[7];
    float* out = (float*)d_out;

    char* ws = (char*)d_ws;
    size_t off = 0;
    auto alloc = [&](size_t bytes) {
        char* p = ws + off;
        off = (off + bytes + 255) & ~(size_t)255;
        return p;
    };
    int* deg_out    = (int*)alloc(NODES * 4);
    int* deg_in     = (int*)alloc(NODES * 4);
    float* out_norm = (float*)alloc(NODES * 4);
    float* in_norm  = (float*)alloc(NODES * 4);
    int* row_start  = (int*)alloc((NODES + 1) * 4);
    int* cursor     = (int*)alloc(NODES * 4);
    int* src_sorted = (int*)alloc(EDGES * 4);
    int* block_sums = (int*)alloc(SCAN_BLOCKS * 4);
    float* norm_sum = (float*)alloc(4);
    float* factor   = (float*)alloc(4);
    ushort* W1T     = (ushort*)alloc((size_t)DIM * FIN * 2);   // [256][128]
    ushort* W2T     = (ushort*)alloc((size_t)DIM * DIM * 2);   // [256][256]
    // Aliased feature regions:
    // P0 (12.8MB): xs [PAD_M][128] bf16   -> later low half of A2
    // P1 (12.8MB): A1 [PAD_M][128] bf16   -> later high half of A2
    // H  (25.6MB): h1s [PAD_M][256] bf16  -> later low half of h2
    // Q  (25.6MB): high half of h2 [PAD_M][256] f32
    ushort* xs  = (ushort*)alloc((size_t)PAD_M * FIN * 2);
    ushort* A1  = (ushort*)alloc((size_t)PAD_M * FIN * 2);
    ushort* h1s = (ushort*)alloc((size_t)PAD_M * DIM * 2);
    alloc((size_t)PAD_M * DIM * 2);  // Q
    ushort* A2 = xs;                  // [PAD_M][256] bf16, overlays P0+P1
    float*  h2 = (float*)h1s;         // [PAD_M][256] f32, overlays H+Q

    hipMemsetAsync(deg_out, 0, NODES * 4, stream);
    hipMemsetAsync(deg_in, 0, NODES * 4, stream);
    hipMemsetAsync(norm_sum, 0, 4, stream);
    hipMemsetAsync(d_out, 0, (size_t)out_size * 4, stream);

    degree_kernel<<<(EDGES + 255) / 256, 256, 0, stream>>>(src, dst, deg_out, deg_in, EDGES);
    norm_kernel<<<(NODES + 255) / 256, 256, 0, stream>>>(deg_out, deg_in, out_norm, in_norm, NODES);
    scan_partials<<<SCAN_BLOCKS, 256, 0, stream>>>(deg_in, block_sums, NODES);
    scan_blocksums<<<1, 256, 0, stream>>>(block_sums, row_start, SCAN_BLOCKS, NODES);
    scan_final<<<SCAN_BLOCKS, 256, 0, stream>>>(deg_in, block_sums, row_start, cursor, NODES);
    scatter_kernel<<<(EDGES + 255) / 256, 256, 0, stream>>>(src, dst, cursor, src_sorted, EDGES);

    prescale_x_kernel<<<(NODES * FIN / 4 + 255) / 256, 256, 0, stream>>>(x, out_norm, xs);
    castW_kernel<FIN><<<(FIN * DIM + 255) / 256, 256, 0, stream>>>(W1, W1T);
    castW_kernel<DIM><<<(DIM * DIM + 255) / 256, 256, 0, stream>>>(W2, W2T);

    // Layer 1
    agg_kernel<FIN><<<(NODES + 3) / 4, 256, 0, stream>>>(xs, row_start, src_sorted, in_norm, A1);
    gemm_mfma_kernel<FIN, 0><<<PAD_M / 64, 256, 0, stream>>>(A1, W1T, b1, h1s, out_norm, NODES);

    // Layer 2
    agg_kernel<DIM><<<(NODES + 3) / 4, 256, 0, stream>>>(h1s, row_start, src_sorted, in_norm, A2);
    gemm_mfma_kernel<DIM, 1><<<PAD_M / 64, 256, 0, stream>>>(A2, W2T, b2, h2, nullptr, NODES);

    // Scale factor and sum-pool
    rownorm_kernel<<<256, 256, 0, stream>>>(h2, norm_sum, NODES);
    factor_kernel<<<1, 1, 0, stream>>>(norm_sum, factor);
    pool_kernel<<<NODES, DIM, 0, stream>>>(h2, n2g, factor, out);
}

// Round 5
// 331.730 us; speedup vs baseline: 3.9954x; 1.2639x over previous
//
#include <hip/hip_runtime.h>

#define NODES 50000
#define EDGES 800000
#define FIN 128
#define DIM 256
#define GRAPHS 256
#define PAD_M 50048   // 782 * 64
#define SCAN_BLOCKS ((NODES + 255) / 256)       // 196
#define PRESCALE_BLOCKS (NODES * FIN / 4 / 256) // 6250 exact

typedef short short8 __attribute__((ext_vector_type(8)));
typedef float f32x4 __attribute__((ext_vector_type(4)));

__device__ __forceinline__ float bf2f(uint u) { return __uint_as_float(u << 16); }
__device__ __forceinline__ ushort f2bf(float f) {
    uint b = __float_as_uint(f);
    return (ushort)((b + 0x7FFF + ((b >> 16) & 1)) >> 16);
}

__global__ void degree_kernel(const int* __restrict__ src, const int* __restrict__ dst,
                              int* __restrict__ deg_out, int* __restrict__ deg_in, int e) {
    int i = blockIdx.x * blockDim.x + threadIdx.x;
    if (i < e) {
        atomicAdd(&deg_out[src[i]], 1);
        atomicAdd(&deg_in[dst[i]], 1);
    }
}

// Phase 1 of scan + fused norm computation (degrees are final here).
__global__ __launch_bounds__(256) void scan_partials(const int* __restrict__ deg_in,
                                                     const int* __restrict__ deg_out,
                                                     int* __restrict__ block_sums,
                                                     float* __restrict__ out_norm,
                                                     float* __restrict__ in_norm, int n) {
    __shared__ int red[4];
    int i = blockIdx.x * 256 + threadIdx.x;
    int v = (i < n) ? deg_in[i] : 0;
    if (i < n) {
        out_norm[i] = rsqrtf(fmaxf((float)deg_out[i], 1.0f));
        in_norm[i]  = rsqrtf(fmaxf((float)v, 1.0f));
    }
    int wave = threadIdx.x >> 6, lane = threadIdx.x & 63;
    int s = v;
#pragma unroll
    for (int off = 32; off > 0; off >>= 1) s += __shfl_down(s, off);
    if (lane == 0) red[wave] = s;
    __syncthreads();
    if (threadIdx.x == 0) block_sums[blockIdx.x] = red[0] + red[1] + red[2] + red[3];
}

// Phase 2: scan the block sums (nb <= 256); also zero norm_sum for this launch.
__global__ __launch_bounds__(256) void scan_blocksums(int* __restrict__ block_sums,
                                                      int* __restrict__ row_start,
                                                      float* __restrict__ norm_sum, int nb, int n) {
    __shared__ int s[256];
    int t = threadIdx.x;
    if (t == 0) *norm_sum = 0.0f;
    int v = (t < nb) ? block_sums[t] : 0;
    s[t] = v;
    __syncthreads();
#pragma unroll
    for (int off = 1; off < 256; off <<= 1) {
        int u = (t >= off) ? s[t - off] : 0;
        __syncthreads();
        s[t] += u;
        __syncthreads();
    }
    if (t < nb) block_sums[t] = s[t] - v;          // exclusive prefix
    if (t == nb - 1) row_start[n] = s[t];          // total
}

// Phase 3: intra-block exclusive scan + block offset -> row_start, cursor.
__global__ __launch_bounds__(256) void scan_final(const int* __restrict__ deg,
                                                  const int* __restrict__ block_sums,
                                                  int* __restrict__ row_start,
                                                  int* __restrict__ cursor, int n) {
    __shared__ int s[256];
    int t = threadIdx.x;
    int i = blockIdx.x * 256 + t;
    int v = (i < n) ? deg[i] : 0;
    s[t] = v;
    __syncthreads();
#pragma unroll
    for (int off = 1; off < 256; off <<= 1) {
        int u = (t >= off) ? s[t - off] : 0;
        __syncthreads();
        s[t] += u;
        __syncthreads();
    }
    if (i < n) {
        int excl = block_sums[blockIdx.x] + s[t] - v;
        row_start[i] = excl;
        cursor[i] = excl;
    }
}

__global__ void scatter_kernel(const int* __restrict__ src, const int* __restrict__ dst,
                               int* __restrict__ cursor, int* __restrict__ src_sorted, int e) {
    int i = blockIdx.x * blockDim.x + threadIdx.x;
    if (i < e) {
        int d = dst[i];
        int pos = atomicAdd(&cursor[d], 1);
        src_sorted[pos] = src[i];
    }
}

// Fused: xs = bf16(x * out_norm[row]) | W1T = bf16(W1^T) | W2T = bf16(W2^T).
__global__ __launch_bounds__(256) void prep_kernel(const float* __restrict__ x,
                                                   const float* __restrict__ out_norm,
                                                   ushort* __restrict__ xs,
                                                   const float* __restrict__ W1,
                                                   ushort* __restrict__ W1T,
                                                   const float* __restrict__ W2,
                                                   ushort* __restrict__ W2T) {
    int b = blockIdx.x;
    if (b < PRESCALE_BLOCKS) {
        int t = b * 256 + threadIdx.x;            // < NODES*FIN/4
        int row = t >> 5;                         // FIN/4 = 32 float4 per row
        float on = out_norm[row];
        float4 v = ((const float4*)x)[t];
        ushort4 o;
        o.x = f2bf(v.x * on); o.y = f2bf(v.y * on);
        o.z = f2bf(v.z * on); o.w = f2bf(v.w * on);
        ((ushort4*)xs)[t] = o;
    } else if (b < PRESCALE_BLOCKS + FIN * DIM / 256) {
        int t = (b - PRESCALE_BLOCKS) * 256 + threadIdx.x;   // < 32768
        int n = t >> 7, k = t & 127;
        W1T[t] = f2bf(W1[(size_t)k * DIM + n]);
    } else {
        int t = (b - PRESCALE_BLOCKS - FIN * DIM / 256) * 256 + threadIdx.x;  // < 65536
        int n = t >> 8, k = t & 255;
        W2T[t] = f2bf(W2[(size_t)k * DIM + n]);
    }
}

// Gather-sum aggregation, bf16 in/out, fp32 accumulate. One wave per node.
// 4-edge unroll for memory-level parallelism (latency-bound kernel).
template<int D>
__global__ __launch_bounds__(256) void agg_kernel(const ushort* __restrict__ in,
                                                  const int* __restrict__ row_start,
                                                  const int* __restrict__ src_sorted,
                                                  const float* __restrict__ in_norm,
                                                  ushort* __restrict__ out) {
    constexpr int VPL = D / 64;       // bf16 per lane (2 or 4)
    constexpr int NU = VPL / 2;       // uint loads per lane
    int wave = threadIdx.x >> 6, lane = threadIdx.x & 63;
    int node = blockIdx.x * 4 + wave;
    if (node >= NODES) return;
    int off = lane * VPL;
    int e0 = row_start[node], e1 = row_start[node + 1];
    float acc[VPL] = {};
    int e = e0;
    for (; e + 3 < e1; e += 4) {
        int s0 = src_sorted[e], s1 = src_sorted[e + 1];
        int s2 = src_sorted[e + 2], s3 = src_sorted[e + 3];
        const uint* p0 = (const uint*)(in + (size_t)s0 * D + off);
        const uint* p1 = (const uint*)(in + (size_t)s1 * D + off);
        const uint* p2 = (const uint*)(in + (size_t)s2 * D + off);
        const uint* p3 = (const uint*)(in + (size_t)s3 * D + off);
        uint u0[NU], u1[NU], u2[NU], u3[NU];
#pragma unroll
        for (int q = 0; q < NU; ++q) { u0[q] = p0[q]; u1[q] = p1[q]; u2[q] = p2[q]; u3[q] = p3[q]; }
#pragma unroll
        for (int q = 0; q < NU; ++q) {
            acc[2*q]   += (bf2f(u0[q] & 0xFFFFu) + bf2f(u1[q] & 0xFFFFu))
                        + (bf2f(u2[q] & 0xFFFFu) + bf2f(u3[q] & 0xFFFFu));
            acc[2*q+1] += (bf2f(u0[q] >> 16) + bf2f(u1[q] >> 16))
                        + (bf2f(u2[q] >> 16) + bf2f(u3[q] >> 16));
        }
    }
    for (; e < e1; ++e) {
        int s0 = src_sorted[e];
        const uint* p0 = (const uint*)(in + (size_t)s0 * D + off);
#pragma unroll
        for (int q = 0; q < NU; ++q) {
            uint u = p0[q];
            acc[2*q]   += bf2f(u & 0xFFFFu);
            acc[2*q+1] += bf2f(u >> 16);
        }
    }
    float inn = in_norm[node];
    uint* po = (uint*)(out + (size_t)node * D + off);
#pragma unroll
    for (int q = 0; q < NU; ++q) {
        uint lo = f2bf(acc[2*q] * inn);
        uint hi = f2bf(acc[2*q+1] * inn);
        po[q] = lo | (hi << 16);
    }
}

// MFMA GEMM: C[M,256] = A[M,K](bf16) @ W + bias. WT[256][K] bf16, no LDS staging.
// MODE 0: out bf16 = relu(acc+bias)*scale[row]     (h1s, pre-scaled for next gather)
// MODE 1: out bf16 = acc+bias, fused row-L2-norm accumulation into norm_sum
template<int K, int MODE>
__global__ __launch_bounds__(256) void gemm_mfma_kernel(const ushort* __restrict__ A,
                                                        const ushort* __restrict__ WT,
                                                        const float* __restrict__ bias,
                                                        ushort* __restrict__ Cout,
                                                        const float* __restrict__ scale,
                                                        float* __restrict__ norm_sum,
                                                        int M) {
    __shared__ float rowsq[4][64];
    int lane = threadIdx.x & 63, wave = threadIdx.x >> 6;
    int m0 = blockIdx.x * 64, n0 = wave * 64;
    int ll = lane & 15, lh = lane >> 4;
    f32x4 acc[4][4] = {};
    const ushort* Ab = A  + (size_t)(m0 + ll) * K + lh * 8;
    const ushort* Bb = WT + (size_t)(n0 + ll) * K + lh * 8;
#pragma unroll
    for (int k0 = 0; k0 < K; k0 += 32) {
        short8 a[4], b[4];
#pragma unroll
        for (int mi = 0; mi < 4; ++mi) a[mi] = *(const short8*)(Ab + (size_t)mi * 16 * K + k0);
#pragma unroll
        for (int ni = 0; ni < 4; ++ni) b[ni] = *(const short8*)(Bb + (size_t)ni * 16 * K + k0);
#pragma unroll
        for (int mi = 0; mi < 4; ++mi)
#pragma unroll
            for (int ni = 0; ni < 4; ++ni)
                acc[mi][ni] = __builtin_amdgcn_mfma_f32_16x16x32_bf16(a[mi], b[ni], acc[mi][ni], 0, 0, 0);
    }
#pragma unroll
    for (int mi = 0; mi < 4; ++mi) {
#pragma unroll
        for (int r = 0; r < 4; ++r) {
            int row = m0 + mi * 16 + lh * 4 + r;
            float sc = (MODE == 0 && row < M) ? scale[row] : 1.0f;
            float p = 0.0f;
#pragma unroll
            for (int ni = 0; ni < 4; ++ni) {
                int col = n0 + ni * 16 + ll;
                float v = acc[mi][ni][r] + bias[col];
                if (MODE == 0) v = fmaxf(v, 0.0f) * sc;
                else p += v * v;
                if (row < M) Cout[(size_t)row * DIM + col] = f2bf(v);
            }
            if (MODE == 1) {
                // reduce p over the 16-lane ll group -> per-row partial for this wave
#pragma unroll
                for (int m = 1; m < 16; m <<= 1) p += __shfl_xor(p, m);
                if (ll == 0) rowsq[wave][mi * 16 + lh * 4 + r] = p;
            }
        }
    }
    if (MODE == 1) {
        __syncthreads();
        if (threadIdx.x < 64) {
            int lr = threadIdx.x;
            float s = rowsq[0][lr] + rowsq[1][lr] + rowsq[2][lr] + rowsq[3][lr];
            float l = (m0 + lr < M) ? sqrtf(s) : 0.0f;
#pragma unroll
            for (int m = 32; m > 0; m >>= 1) l += __shfl_down(l, m);
            if (lr == 0) atomicAdd(norm_sum, l);
        }
    }
}

// One block per graph (n2g is sorted): binary-search node range, no atomics,
// factor computed inline. Writes every output element exactly once.
__global__ __launch_bounds__(256) void pool_kernel(const ushort* __restrict__ h2,
                                                   const int* __restrict__ n2g,
                                                   const float* __restrict__ norm_sum,
                                                   float* __restrict__ out) {
    int g = blockIdx.x, f = threadIdx.x;
    int lo = 0, hi = NODES;
    while (lo < hi) { int mid = (lo + hi) >> 1; if (n2g[mid] < g) lo = mid + 1; else hi = mid; }
    int start = lo;
    hi = NODES;
    while (lo < hi) { int mid = (lo + hi) >> 1; if (n2g[mid] < g + 1) lo = mid + 1; else hi = mid; }
    int end = lo;
    float acc = 0.0f;
    int i = start;
    for (; i + 3 < end; i += 4) {
        acc += (bf2f((uint)h2[(size_t)(i + 0) * DIM + f]) + bf2f((uint)h2[(size_t)(i + 1) * DIM + f]))
             + (bf2f((uint)h2[(size_t)(i + 2) * DIM + f]) + bf2f((uint)h2[(size_t)(i + 3) * DIM + f]));
    }
    for (; i < end; ++i) acc += bf2f((uint)h2[(size_t)i * DIM + f]);
    float factor = 16.0f * (float)NODES / *norm_sum;   // sqrt(256) / mean row norm
    out[(size_t)g * DIM + f] = acc * factor;
}

extern "C" void kernel_launch(void* const* d_in, const int* in_sizes, int n_in,
                              void* d_out, int out_size, void* d_ws, size_t ws_size,
                              hipStream_t stream) {
    const float* x  = (const float*)d_in[0];
    const float* W1 = (const float*)d_in[1];
    const float* b1 = (const float*)d_in[2];
    const float* W2 = (const float*)d_in[3];
    const float* b2 = (const float*)d_in[4];
    const int* src = (const int*)d_in[5];
    const int* dst = (const int*)d_in[6];
    const int* n2g = (const int*)d_in[7];
    float* out = (float*)d_out;

    char* ws = (char*)d_ws;
    size_t off = 0;
    auto alloc = [&](size_t bytes) {
        char* p = ws + off;
        off = (off + bytes + 255) & ~(size_t)255;
        return p;
    };
    int* deg        = (int*)alloc((size_t)2 * NODES * 4);  // [deg_out | deg_in]
    int* deg_out    = deg;
    int* deg_in     = deg + NODES;
    float* out_norm = (float*)alloc(NODES * 4);
    float* in_norm  = (float*)alloc(NODES * 4);
    int* row_start  = (int*)alloc((NODES + 1) * 4);
    int* cursor     = (int*)alloc(NODES * 4);
    int* src_sorted = (int*)alloc(EDGES * 4);
    int* block_sums = (int*)alloc(SCAN_BLOCKS * 4);
    float* norm_sum = (float*)alloc(4);
    ushort* W1T     = (ushort*)alloc((size_t)DIM * FIN * 2);   // [256][128]
    ushort* W2T     = (ushort*)alloc((size_t)DIM * DIM * 2);   // [256][256]
    // Aliased feature regions:
    // P0: xs [PAD_M][128] bf16 -> low half of A2 | P1: A1 [PAD_M][128] -> high half of A2
    // H : h1s [PAD_M][256] bf16 -> reused as h2 [PAD_M][256] bf16 (agg2 consumed h1s before gemm2 writes)
    ushort* xs  = (ushort*)alloc((size_t)PAD_M * FIN * 2);
    ushort* A1  = (ushort*)alloc((size_t)PAD_M * FIN * 2);
    ushort* h1s = (ushort*)alloc((size_t)PAD_M * DIM * 2);
    ushort* A2 = xs;          // [PAD_M][256] bf16, overlays P0+P1
    ushort* h2 = h1s;         // [PAD_M][256] bf16, overlays H

    hipMemsetAsync(deg, 0, (size_t)2 * NODES * 4, stream);

    degree_kernel<<<(EDGES + 255) / 256, 256, 0, stream>>>(src, dst, deg_out, deg_in, EDGES);
    scan_partials<<<SCAN_BLOCKS, 256, 0, stream>>>(deg_in, deg_out, block_sums, out_norm, in_norm, NODES);
    scan_blocksums<<<1, 256, 0, stream>>>(block_sums, row_start, norm_sum, SCAN_BLOCKS, NODES);
    scan_final<<<SCAN_BLOCKS, 256, 0, stream>>>(deg_in, block_sums, row_start, cursor, NODES);
    scatter_kernel<<<(EDGES + 255) / 256, 256, 0, stream>>>(src, dst, cursor, src_sorted, EDGES);

    prep_kernel<<<PRESCALE_BLOCKS + FIN * DIM / 256 + DIM * DIM / 256, 256, 0, stream>>>(
        x, out_norm, xs, W1, W1T, W2, W2T);

    // Layer 1
    agg_kernel<FIN><<<(NODES + 3) / 4, 256, 0, stream>>>(xs, row_start, src_sorted, in_norm, A1);
    gemm_mfma_kernel<FIN, 0><<<PAD_M / 64, 256, 0, stream>>>(A1, W1T, b1, h1s, out_norm, norm_sum, NODES);

    // Layer 2 (gemm2 fuses row-norm accumulation, writes bf16 h2)
    agg_kernel<DIM><<<(NODES + 3) / 4, 256, 0, stream>>>(h1s, row_start, src_sorted, in_norm, A2);
    gemm_mfma_kernel<DIM, 1><<<PAD_M / 64, 256, 0, stream>>>(A2, W2T, b2, h2, nullptr, norm_sum, NODES);

    // Per-graph sum-pool with inline factor; covers all graphs, no memset needed.
    pool_kernel<<<GRAPHS, 256, 0, stream>>>(h2, n2g, norm_sum, out);
}

// Round 6
// 318.074 us; speedup vs baseline: 4.1669x; 1.0429x over previous
//
#include <hip/hip_runtime.h>

#define NODES 50000
#define EDGES 800000
#define FIN 128
#define DIM 256
#define GRAPHS 256
#define PAD_M 50048   // 782 * 64
#define SCAN_BLOCKS ((NODES + 255) / 256)       // 196
#define EDGE_BLOCKS ((EDGES + 255) / 256)       // 3125
#define PRESCALE_BLOCKS (NODES * FIN / 4 / 256) // 6250 exact
#define NCOPY 8                                 // XCD-privatized histogram copies

typedef short short8 __attribute__((ext_vector_type(8)));
typedef float f32x4 __attribute__((ext_vector_type(4)));

__device__ __forceinline__ float bf2f(uint u) { return __uint_as_float(u << 16); }
__device__ __forceinline__ ushort f2bf(float f) {
    uint b = __float_as_uint(f);
    return (ushort)((b + 0x7FFF + ((b >> 16) & 1)) >> 16);
}

// Privatized degree histogram: copy c = blockIdx.x & 7.
// degP[c][i]        = out-degree partial (src)
// degP[c][NODES+i]  = in-degree partial  (dst)
__global__ void degree_kernel(const int* __restrict__ src, const int* __restrict__ dst,
                              int* __restrict__ degP, int e) {
    int i = blockIdx.x * blockDim.x + threadIdx.x;
    int* my = degP + (size_t)(blockIdx.x & (NCOPY - 1)) * 2 * NODES;
    if (i < e) {
        atomicAdd(&my[src[i]], 1);
        atomicAdd(&my[NODES + dst[i]], 1);
    }
}

// Phase 1 of scan + copy-reduction + fused norm computation.
__global__ __launch_bounds__(256) void scan_partials(const int* __restrict__ degP,
                                                     int* __restrict__ block_sums,
                                                     float* __restrict__ out_norm,
                                                     float* __restrict__ in_norm,
                                                     int* __restrict__ deg_in, int n) {
    __shared__ int red[4];
    int i = blockIdx.x * 256 + threadIdx.x;
    int din = 0;
    if (i < n) {
        int dout = 0;
#pragma unroll
        for (int c = 0; c < NCOPY; ++c) {
            dout += degP[(size_t)c * 2 * NODES + i];
            din  += degP[(size_t)c * 2 * NODES + NODES + i];
        }
        out_norm[i] = rsqrtf(fmaxf((float)dout, 1.0f));
        in_norm[i]  = rsqrtf(fmaxf((float)din, 1.0f));
        deg_in[i] = din;
    }
    int wave = threadIdx.x >> 6, lane = threadIdx.x & 63;
    int s = din;
#pragma unroll
    for (int off = 32; off > 0; off >>= 1) s += __shfl_down(s, off);
    if (lane == 0) red[wave] = s;
    __syncthreads();
    if (threadIdx.x == 0) block_sums[blockIdx.x] = red[0] + red[1] + red[2] + red[3];
}

// Phase 2: scan the block sums (nb <= 256); also zero norm_sum for this launch.
__global__ __launch_bounds__(256) void scan_blocksums(int* __restrict__ block_sums,
                                                      int* __restrict__ row_start,
                                                      float* __restrict__ norm_sum, int nb, int n) {
    __shared__ int s[256];
    int t = threadIdx.x;
    if (t == 0) *norm_sum = 0.0f;
    int v = (t < nb) ? block_sums[t] : 0;
    s[t] = v;
    __syncthreads();
#pragma unroll
    for (int off = 1; off < 256; off <<= 1) {
        int u = (t >= off) ? s[t - off] : 0;
        __syncthreads();
        s[t] += u;
        __syncthreads();
    }
    if (t < nb) block_sums[t] = s[t] - v;          // exclusive prefix
    if (t == nb - 1) row_start[n] = s[t];          // total
}

// Phase 3: intra-block exclusive scan + block offset -> row_start,
// plus per-copy cursor bases: cursorP[c][i] = row_start[i] + sum_{c'<c} cnt[c'][i].
__global__ __launch_bounds__(256) void scan_final(const int* __restrict__ deg,
                                                  const int* __restrict__ degP,
                                                  const int* __restrict__ block_sums,
                                                  int* __restrict__ row_start,
                                                  int* __restrict__ cursorP, int n) {
    __shared__ int s[256];
    int t = threadIdx.x;
    int i = blockIdx.x * 256 + t;
    int v = (i < n) ? deg[i] : 0;
    s[t] = v;
    __syncthreads();
#pragma unroll
    for (int off = 1; off < 256; off <<= 1) {
        int u = (t >= off) ? s[t - off] : 0;
        __syncthreads();
        s[t] += u;
        __syncthreads();
    }
    if (i < n) {
        int excl = block_sums[blockIdx.x] + s[t] - v;
        row_start[i] = excl;
        int run = excl;
#pragma unroll
        for (int c = 0; c < NCOPY; ++c) {
            cursorP[(size_t)c * NODES + i] = run;
            run += degP[(size_t)c * 2 * NODES + NODES + i];
        }
    }
}

// Scatter with privatized cursors. Copy assignment (blockIdx.x & 7) matches
// degree_kernel's block->edge mapping exactly, so each copy's reserved slot
// ranges are disjoint and exact.
__global__ void scatter_kernel(const int* __restrict__ src, const int* __restrict__ dst,
                               int* __restrict__ cursorP, int* __restrict__ src_sorted, int e) {
    int i = blockIdx.x * blockDim.x + threadIdx.x;
    int* my = cursorP + (size_t)(blockIdx.x & (NCOPY - 1)) * NODES;
    if (i < e) {
        int d = dst[i];
        int pos = atomicAdd(&my[d], 1);
        src_sorted[pos] = src[i];
    }
}

// Fused: xs = bf16(x * out_norm[row]) | W1T = bf16(W1^T) | W2T = bf16(W2^T).
__global__ __launch_bounds__(256) void prep_kernel(const float* __restrict__ x,
                                                   const float* __restrict__ out_norm,
                                                   ushort* __restrict__ xs,
                                                   const float* __restrict__ W1,
                                                   ushort* __restrict__ W1T,
                                                   const float* __restrict__ W2,
                                                   ushort* __restrict__ W2T) {
    int b = blockIdx.x;
    if (b < PRESCALE_BLOCKS) {
        int t = b * 256 + threadIdx.x;            // < NODES*FIN/4
        int row = t >> 5;                         // FIN/4 = 32 float4 per row
        float on = out_norm[row];
        float4 v = ((const float4*)x)[t];
        ushort4 o;
        o.x = f2bf(v.x * on); o.y = f2bf(v.y * on);
        o.z = f2bf(v.z * on); o.w = f2bf(v.w * on);
        ((ushort4*)xs)[t] = o;
    } else if (b < PRESCALE_BLOCKS + FIN * DIM / 256) {
        int t = (b - PRESCALE_BLOCKS) * 256 + threadIdx.x;   // < 32768
        int n = t >> 7, k = t & 127;
        W1T[t] = f2bf(W1[(size_t)k * DIM + n]);
    } else {
        int t = (b - PRESCALE_BLOCKS - FIN * DIM / 256) * 256 + threadIdx.x;  // < 65536
        int n = t >> 8, k = t & 255;
        W2T[t] = f2bf(W2[(size_t)k * DIM + n]);
    }
}

// Gather-sum aggregation, bf16 in/out, fp32 accumulate. One wave per node.
// 4-edge unroll for memory-level parallelism (latency-bound kernel).
template<int D>
__global__ __launch_bounds__(256) void agg_kernel(const ushort* __restrict__ in,
                                                  const int* __restrict__ row_start,
                                                  const int* __restrict__ src_sorted,
                                                  const float* __restrict__ in_norm,
                                                  ushort* __restrict__ out) {
    constexpr int VPL = D / 64;       // bf16 per lane (2 or 4)
    constexpr int NU = VPL / 2;       // uint loads per lane
    int wave = threadIdx.x >> 6, lane = threadIdx.x & 63;
    int node = blockIdx.x * 4 + wave;
    if (node >= NODES) return;
    int off = lane * VPL;
    int e0 = row_start[node], e1 = row_start[node + 1];
    float acc[VPL] = {};
    int e = e0;
    for (; e + 3 < e1; e += 4) {
        int s0 = src_sorted[e], s1 = src_sorted[e + 1];
        int s2 = src_sorted[e + 2], s3 = src_sorted[e + 3];
        const uint* p0 = (const uint*)(in + (size_t)s0 * D + off);
        const uint* p1 = (const uint*)(in + (size_t)s1 * D + off);
        const uint* p2 = (const uint*)(in + (size_t)s2 * D + off);
        const uint* p3 = (const uint*)(in + (size_t)s3 * D + off);
        uint u0[NU], u1[NU], u2[NU], u3[NU];
#pragma unroll
        for (int q = 0; q < NU; ++q) { u0[q] = p0[q]; u1[q] = p1[q]; u2[q] = p2[q]; u3[q] = p3[q]; }
#pragma unroll
        for (int q = 0; q < NU; ++q) {
            acc[2*q]   += (bf2f(u0[q] & 0xFFFFu) + bf2f(u1[q] & 0xFFFFu))
                        + (bf2f(u2[q] & 0xFFFFu) + bf2f(u3[q] & 0xFFFFu));
            acc[2*q+1] += (bf2f(u0[q] >> 16) + bf2f(u1[q] >> 16))
                        + (bf2f(u2[q] >> 16) + bf2f(u3[q] >> 16));
        }
    }
    for (; e < e1; ++e) {
        int s0 = src_sorted[e];
        const uint* p0 = (const uint*)(in + (size_t)s0 * D + off);
#pragma unroll
        for (int q = 0; q < NU; ++q) {
            uint u = p0[q];
            acc[2*q]   += bf2f(u & 0xFFFFu);
            acc[2*q+1] += bf2f(u >> 16);
        }
    }
    float inn = in_norm[node];
    uint* po = (uint*)(out + (size_t)node * D + off);
#pragma unroll
    for (int q = 0; q < NU; ++q) {
        uint lo = f2bf(acc[2*q] * inn);
        uint hi = f2bf(acc[2*q+1] * inn);
        po[q] = lo | (hi << 16);
    }
}

// MFMA GEMM: C[M,256] = A[M,K](bf16) @ W + bias. WT[256][K] bf16, no LDS staging.
// MODE 0: out bf16 = relu(acc+bias)*scale[row]     (h1s, pre-scaled for next gather)
// MODE 1: out bf16 = acc+bias, fused row-L2-norm accumulation into norm_sum
template<int K, int MODE>
__global__ __launch_bounds__(256) void gemm_mfma_kernel(const ushort* __restrict__ A,
                                                        const ushort* __restrict__ WT,
                                                        const float* __restrict__ bias,
                                                        ushort* __restrict__ Cout,
                                                        const float* __restrict__ scale,
                                                        float* __restrict__ norm_sum,
                                                        int M) {
    __shared__ float rowsq[4][64];
    int lane = threadIdx.x & 63, wave = threadIdx.x >> 6;
    int m0 = blockIdx.x * 64, n0 = wave * 64;
    int ll = lane & 15, lh = lane >> 4;
    f32x4 acc[4][4] = {};
    const ushort* Ab = A  + (size_t)(m0 + ll) * K + lh * 8;
    const ushort* Bb = WT + (size_t)(n0 + ll) * K + lh * 8;
#pragma unroll
    for (int k0 = 0; k0 < K; k0 += 32) {
        short8 a[4], b[4];
#pragma unroll
        for (int mi = 0; mi < 4; ++mi) a[mi] = *(const short8*)(Ab + (size_t)mi * 16 * K + k0);
#pragma unroll
        for (int ni = 0; ni < 4; ++ni) b[ni] = *(const short8*)(Bb + (size_t)ni * 16 * K + k0);
#pragma unroll
        for (int mi = 0; mi < 4; ++mi)
#pragma unroll
            for (int ni = 0; ni < 4; ++ni)
                acc[mi][ni] = __builtin_amdgcn_mfma_f32_16x16x32_bf16(a[mi], b[ni], acc[mi][ni], 0, 0, 0);
    }
#pragma unroll
    for (int mi = 0; mi < 4; ++mi) {
#pragma unroll
        for (int r = 0; r < 4; ++r) {
            int row = m0 + mi * 16 + lh * 4 + r;
            float sc = (MODE == 0 && row < M) ? scale[row] : 1.0f;
            float p = 0.0f;
#pragma unroll
            for (int ni = 0; ni < 4; ++ni) {
                int col = n0 + ni * 16 + ll;
                float v = acc[mi][ni][r] + bias[col];
                if (MODE == 0) v = fmaxf(v, 0.0f) * sc;
                else p += v * v;
                if (row < M) Cout[(size_t)row * DIM + col] = f2bf(v);
            }
            if (MODE == 1) {
                // reduce p over the 16-lane ll group -> per-row partial for this wave
#pragma unroll
                for (int m = 1; m < 16; m <<= 1) p += __shfl_xor(p, m);
                if (ll == 0) rowsq[wave][mi * 16 + lh * 4 + r] = p;
            }
        }
    }
    if (MODE == 1) {
        __syncthreads();
        if (threadIdx.x < 64) {
            int lr = threadIdx.x;
            float s = rowsq[0][lr] + rowsq[1][lr] + rowsq[2][lr] + rowsq[3][lr];
            float l = (m0 + lr < M) ? sqrtf(s) : 0.0f;
#pragma unroll
            for (int m = 32; m > 0; m >>= 1) l += __shfl_down(l, m);
            if (lr == 0) atomicAdd(norm_sum, l);
        }
    }
}

// One block per graph (n2g is sorted): binary-search node range, no atomics,
// factor computed inline. Writes every output element exactly once.
__global__ __launch_bounds__(256) void pool_kernel(const ushort* __restrict__ h2,
                                                   const int* __restrict__ n2g,
                                                   const float* __restrict__ norm_sum,
                                                   float* __restrict__ out) {
    int g = blockIdx.x, f = threadIdx.x;
    int lo = 0, hi = NODES;
    while (lo < hi) { int mid = (lo + hi) >> 1; if (n2g[mid] < g) lo = mid + 1; else hi = mid; }
    int start = lo;
    hi = NODES;
    while (lo < hi) { int mid = (lo + hi) >> 1; if (n2g[mid] < g + 1) lo = mid + 1; else hi = mid; }
    int end = lo;
    float acc = 0.0f;
    int i = start;
    for (; i + 3 < end; i += 4) {
        acc += (bf2f((uint)h2[(size_t)(i + 0) * DIM + f]) + bf2f((uint)h2[(size_t)(i + 1) * DIM + f]))
             + (bf2f((uint)h2[(size_t)(i + 2) * DIM + f]) + bf2f((uint)h2[(size_t)(i + 3) * DIM + f]));
    }
    for (; i < end; ++i) acc += bf2f((uint)h2[(size_t)i * DIM + f]);
    float factor = 16.0f * (float)NODES / *norm_sum;   // sqrt(256) / mean row norm
    out[(size_t)g * DIM + f] = acc * factor;
}

extern "C" void kernel_launch(void* const* d_in, const int* in_sizes, int n_in,
                              void* d_out, int out_size, void* d_ws, size_t ws_size,
                              hipStream_t stream) {
    const float* x  = (const float*)d_in[0];
    const float* W1 = (const float*)d_in[1];
    const float* b1 = (const float*)d_in[2];
    const float* W2 = (const float*)d_in[3];
    const float* b2 = (const float*)d_in[4];
    const int* src = (const int*)d_in[5];
    const int* dst = (const int*)d_in[6];
    const int* n2g = (const int*)d_in[7];
    float* out = (float*)d_out;

    char* ws = (char*)d_ws;
    size_t off = 0;
    auto alloc = [&](size_t bytes) {
        char* p = ws + off;
        off = (off + bytes + 255) & ~(size_t)255;
        return p;
    };
    int* degP       = (int*)alloc((size_t)NCOPY * 2 * NODES * 4);  // 3.2 MB privatized histograms
    int* cursorP    = (int*)alloc((size_t)NCOPY * NODES * 4);      // 1.6 MB privatized cursors
    int* deg_in     = (int*)alloc(NODES * 4);
    float* out_norm = (float*)alloc(NODES * 4);
    float* in_norm  = (float*)alloc(NODES * 4);
    int* row_start  = (int*)alloc((NODES + 1) * 4);
    int* src_sorted = (int*)alloc(EDGES * 4);
    int* block_sums = (int*)alloc(SCAN_BLOCKS * 4);
    float* norm_sum = (float*)alloc(4);
    ushort* W1T     = (ushort*)alloc((size_t)DIM * FIN * 2);   // [256][128]
    ushort* W2T     = (ushort*)alloc((size_t)DIM * DIM * 2);   // [256][256]
    // Aliased feature regions:
    // P0: xs [PAD_M][128] bf16 -> low half of A2 | P1: A1 [PAD_M][128] -> high half of A2
    // H : h1s [PAD_M][256] bf16 -> reused as h2 (agg2 consumed h1s before gemm2 writes)
    ushort* xs  = (ushort*)alloc((size_t)PAD_M * FIN * 2);
    ushort* A1  = (ushort*)alloc((size_t)PAD_M * FIN * 2);
    ushort* h1s = (ushort*)alloc((size_t)PAD_M * DIM * 2);
    ushort* A2 = xs;          // [PAD_M][256] bf16, overlays P0+P1
    ushort* h2 = h1s;         // [PAD_M][256] bf16, overlays H

    hipMemsetAsync(degP, 0, (size_t)NCOPY * 2 * NODES * 4, stream);

    degree_kernel<<<EDGE_BLOCKS, 256, 0, stream>>>(src, dst, degP, EDGES);
    scan_partials<<<SCAN_BLOCKS, 256, 0, stream>>>(degP, block_sums, out_norm, in_norm, deg_in, NODES);
    scan_blocksums<<<1, 256, 0, stream>>>(block_sums, row_start, norm_sum, SCAN_BLOCKS, NODES);
    scan_final<<<SCAN_BLOCKS, 256, 0, stream>>>(deg_in, degP, block_sums, row_start, cursorP, NODES);
    scatter_kernel<<<EDGE_BLOCKS, 256, 0, stream>>>(src, dst, cursorP, src_sorted, EDGES);

    prep_kernel<<<PRESCALE_BLOCKS + FIN * DIM / 256 + DIM * DIM / 256, 256, 0, stream>>>(
        x, out_norm, xs, W1, W1T, W2, W2T);

    // Layer 1
    agg_kernel<FIN><<<(NODES + 3) / 4, 256, 0, stream>>>(xs, row_start, src_sorted, in_norm, A1);
    gemm_mfma_kernel<FIN, 0><<<PAD_M / 64, 256, 0, stream>>>(A1, W1T, b1, h1s, out_norm, norm_sum, NODES);

    // Layer 2 (gemm2 fuses row-norm accumulation, writes bf16 h2)
    agg_kernel<DIM><<<(NODES + 3) / 4, 256, 0, stream>>>(h1s, row_start, src_sorted, in_norm, A2);
    gemm_mfma_kernel<DIM, 1><<<PAD_M / 64, 256, 0, stream>>>(A2, W2T, b2, h2, nullptr, norm_sum, NODES);

    // Per-graph sum-pool with inline factor; covers all graphs, no memset needed.
    pool_kernel<<<GRAPHS, 256, 0, stream>>>(h2, n2g, norm_sum, out);
}

// Round 7
// 291.673 us; speedup vs baseline: 4.5441x; 1.0905x over previous
//
#include <hip/hip_runtime.h>

#define NODES 50000
#define EDGES 800000
#define FIN 128
#define DIM 256
#define GRAPHS 256
#define PAD_M 50048   // 782 * 64
#define SCAN_BLOCKS ((NODES + 255) / 256)       // 196
#define PRESCALE_BLOCKS (NODES * FIN / 4 / 256) // 6250 exact
#define HBLOCKS 256                             // histogram copies / edge chunks
#define CHUNK (EDGES / HBLOCKS)                 // 3125 edges per block, exact
#define HALF_N 25000                            // nodes per LDS half
#define HALF_W 12500                            // u32 words per half (2 nodes/u32)

typedef short short8 __attribute__((ext_vector_type(8)));
typedef float f32x4 __attribute__((ext_vector_type(4)));

__device__ __forceinline__ float bf2f(uint u) { return __uint_as_float(u << 16); }
__device__ __forceinline__ ushort f2bf(float f) {
    uint b = __float_as_uint(f);
    return (ushort)((b + 0x7FFF + ((b >> 16) & 1)) >> 16);
}

// Per-block LDS histogram of idx[] over its 3125-edge chunk, u16-packed
// (2 nodes per u32; per-block count <= 3125 so no overflow), node range in
// 2 halves of 25000 (50KB LDS each). Dump = streaming writes, NO global atomics.
__global__ __launch_bounds__(256) void hist_kernel(const int* __restrict__ idx,
                                                   uint* __restrict__ histG) {
    __shared__ uint cur[HALF_W];
    int b = blockIdx.x, tid = threadIdx.x;
    int base = b * CHUNK;
    for (int half = 0; half < 2; ++half) {
        for (int j = tid; j < HALF_W; j += 256) cur[j] = 0;
        __syncthreads();
        int lo = half * HALF_N;
        for (int e = base + tid; e < base + CHUNK; e += 256) {
            int local = idx[e] - lo;
            if ((unsigned)local < (unsigned)HALF_N)
                atomicAdd(&cur[local >> 1], 1u << ((local & 1) * 16));
        }
        __syncthreads();
        uint* dstp = histG + (size_t)b * (2 * HALF_W) + half * HALF_W;
        for (int j = tid; j < HALF_W; j += 256) dstp[j] = cur[j];
        __syncthreads();
    }
}

// Sum the 256 copies -> deg_in / norms; in-place transform histIn into
// per-block EXCLUSIVE prefixes (packed u16) = scatter cursor bases.
// histOut is only summed (out_norm).
__global__ __launch_bounds__(256) void reduce_hist_kernel(uint* __restrict__ histIn,
                                                          const uint* __restrict__ histOut,
                                                          int* __restrict__ deg_in,
                                                          float* __restrict__ in_norm,
                                                          float* __restrict__ out_norm) {
    int t32 = blockIdx.x * 256 + threadIdx.x;
    if (t32 >= 2 * HALF_W) return;
    uint lo = 0, hi = 0;
#pragma unroll 4
    for (int c = 0; c < HBLOCKS; ++c) {
        size_t a = (size_t)c * (2 * HALF_W) + t32;
        uint u = histIn[a];
        histIn[a] = lo | (hi << 16);       // exclusive prefix over blocks (fits u16: <= deg)
        lo += u & 0xFFFFu;
        hi += u >> 16;
    }
    uint olo = 0, ohi = 0;
#pragma unroll 4
    for (int c = 0; c < HBLOCKS; ++c) {
        uint u = histOut[(size_t)c * (2 * HALF_W) + t32];
        olo += u & 0xFFFFu;
        ohi += u >> 16;
    }
    int n0 = (t32 < HALF_W) ? 2 * t32 : HALF_N + 2 * (t32 - HALF_W);
    deg_in[n0]     = (int)lo;
    deg_in[n0 + 1] = (int)hi;
    in_norm[n0]      = rsqrtf(fmaxf((float)lo, 1.0f));
    in_norm[n0 + 1]  = rsqrtf(fmaxf((float)hi, 1.0f));
    out_norm[n0]     = rsqrtf(fmaxf((float)olo, 1.0f));
    out_norm[n0 + 1] = rsqrtf(fmaxf((float)ohi, 1.0f));
}

// Phase 1 of row_start scan: per-256-node block sums.
__global__ __launch_bounds__(256) void scan_partials(const int* __restrict__ deg_in,
                                                     int* __restrict__ block_sums, int n) {
    __shared__ int red[4];
    int i = blockIdx.x * 256 + threadIdx.x;
    int v = (i < n) ? deg_in[i] : 0;
    int wave = threadIdx.x >> 6, lane = threadIdx.x & 63;
#pragma unroll
    for (int off = 32; off > 0; off >>= 1) v += __shfl_down(v, off);
    if (lane == 0) red[wave] = v;
    __syncthreads();
    if (threadIdx.x == 0) block_sums[blockIdx.x] = red[0] + red[1] + red[2] + red[3];
}

// Phase 2: scan the block sums (nb <= 256); also zero norm_sum for this launch.
__global__ __launch_bounds__(256) void scan_blocksums(int* __restrict__ block_sums,
                                                      int* __restrict__ row_start,
                                                      float* __restrict__ norm_sum, int nb, int n) {
    __shared__ int s[256];
    int t = threadIdx.x;
    if (t == 0) *norm_sum = 0.0f;
    int v = (t < nb) ? block_sums[t] : 0;
    s[t] = v;
    __syncthreads();
#pragma unroll
    for (int off = 1; off < 256; off <<= 1) {
        int u = (t >= off) ? s[t - off] : 0;
        __syncthreads();
        s[t] += u;
        __syncthreads();
    }
    if (t < nb) block_sums[t] = s[t] - v;          // exclusive prefix
    if (t == nb - 1) row_start[n] = s[t];          // total
}

// Phase 3: intra-block exclusive scan + block offset -> row_start.
__global__ __launch_bounds__(256) void scan_final(const int* __restrict__ deg,
                                                  const int* __restrict__ block_sums,
                                                  int* __restrict__ row_start, int n) {
    __shared__ int s[256];
    int t = threadIdx.x;
    int i = blockIdx.x * 256 + t;
    int v = (i < n) ? deg[i] : 0;
    s[t] = v;
    __syncthreads();
#pragma unroll
    for (int off = 1; off < 256; off <<= 1) {
        int u = (t >= off) ? s[t - off] : 0;
        __syncthreads();
        s[t] += u;
        __syncthreads();
    }
    if (i < n) row_start[i] = block_sums[blockIdx.x] + s[t] - v;
}

// Scatter with LDS cursors seeded from the per-block exclusive prefixes.
// Each block owns disjoint, exact slot ranges per dst node -> no global atomics.
__global__ __launch_bounds__(256) void scatter_lds_kernel(const int* __restrict__ src,
                                                          const int* __restrict__ dst,
                                                          const uint* __restrict__ histIn,
                                                          const int* __restrict__ row_start,
                                                          int* __restrict__ src_sorted) {
    __shared__ uint cur[HALF_W];
    int b = blockIdx.x, tid = threadIdx.x;
    int base = b * CHUNK;
    for (int half = 0; half < 2; ++half) {
        const uint* offp = histIn + (size_t)b * (2 * HALF_W) + half * HALF_W;
        for (int j = tid; j < HALF_W; j += 256) cur[j] = offp[j];
        __syncthreads();
        int lo = half * HALF_N;
        for (int e = base + tid; e < base + CHUNK; e += 256) {
            int d = dst[e];
            int local = d - lo;
            if ((unsigned)local < (unsigned)HALF_N) {
                int sel = (local & 1) * 16;
                uint old = atomicAdd(&cur[local >> 1], 1u << sel);
                int pos = row_start[d] + (int)((old >> sel) & 0xFFFFu);
                src_sorted[pos] = src[e];
            }
        }
        __syncthreads();
    }
}

// Fused: xs = bf16(x * out_norm[row]) | W1T = bf16(W1^T) | W2T = bf16(W2^T).
__global__ __launch_bounds__(256) void prep_kernel(const float* __restrict__ x,
                                                   const float* __restrict__ out_norm,
                                                   ushort* __restrict__ xs,
                                                   const float* __restrict__ W1,
                                                   ushort* __restrict__ W1T,
                                                   const float* __restrict__ W2,
                                                   ushort* __restrict__ W2T) {
    int b = blockIdx.x;
    if (b < PRESCALE_BLOCKS) {
        int t = b * 256 + threadIdx.x;            // < NODES*FIN/4
        int row = t >> 5;                         // FIN/4 = 32 float4 per row
        float on = out_norm[row];
        float4 v = ((const float4*)x)[t];
        ushort4 o;
        o.x = f2bf(v.x * on); o.y = f2bf(v.y * on);
        o.z = f2bf(v.z * on); o.w = f2bf(v.w * on);
        ((ushort4*)xs)[t] = o;
    } else if (b < PRESCALE_BLOCKS + FIN * DIM / 256) {
        int t = (b - PRESCALE_BLOCKS) * 256 + threadIdx.x;   // < 32768
        int n = t >> 7, k = t & 127;
        W1T[t] = f2bf(W1[(size_t)k * DIM + n]);
    } else {
        int t = (b - PRESCALE_BLOCKS - FIN * DIM / 256) * 256 + threadIdx.x;  // < 65536
        int n = t >> 8, k = t & 255;
        W2T[t] = f2bf(W2[(size_t)k * DIM + n]);
    }
}

// Gather-sum aggregation, bf16 in/out, fp32 accumulate. One wave per node.
// 4-edge unroll for memory-level parallelism (latency-bound kernel).
template<int D>
__global__ __launch_bounds__(256) void agg_kernel(const ushort* __restrict__ in,
                                                  const int* __restrict__ row_start,
                                                  const int* __restrict__ src_sorted,
                                                  const float* __restrict__ in_norm,
                                                  ushort* __restrict__ out) {
    constexpr int VPL = D / 64;       // bf16 per lane (2 or 4)
    constexpr int NU = VPL / 2;       // uint loads per lane
    int wave = threadIdx.x >> 6, lane = threadIdx.x & 63;
    int node = blockIdx.x * 4 + wave;
    if (node >= NODES) return;
    int off = lane * VPL;
    int e0 = row_start[node], e1 = row_start[node + 1];
    float acc[VPL] = {};
    int e = e0;
    for (; e + 3 < e1; e += 4) {
        int s0 = src_sorted[e], s1 = src_sorted[e + 1];
        int s2 = src_sorted[e + 2], s3 = src_sorted[e + 3];
        const uint* p0 = (const uint*)(in + (size_t)s0 * D + off);
        const uint* p1 = (const uint*)(in + (size_t)s1 * D + off);
        const uint* p2 = (const uint*)(in + (size_t)s2 * D + off);
        const uint* p3 = (const uint*)(in + (size_t)s3 * D + off);
        uint u0[NU], u1[NU], u2[NU], u3[NU];
#pragma unroll
        for (int q = 0; q < NU; ++q) { u0[q] = p0[q]; u1[q] = p1[q]; u2[q] = p2[q]; u3[q] = p3[q]; }
#pragma unroll
        for (int q = 0; q < NU; ++q) {
            acc[2*q]   += (bf2f(u0[q] & 0xFFFFu) + bf2f(u1[q] & 0xFFFFu))
                        + (bf2f(u2[q] & 0xFFFFu) + bf2f(u3[q] & 0xFFFFu));
            acc[2*q+1] += (bf2f(u0[q] >> 16) + bf2f(u1[q] >> 16))
                        + (bf2f(u2[q] >> 16) + bf2f(u3[q] >> 16));
        }
    }
    for (; e < e1; ++e) {
        int s0 = src_sorted[e];
        const uint* p0 = (const uint*)(in + (size_t)s0 * D + off);
#pragma unroll
        for (int q = 0; q < NU; ++q) {
            uint u = p0[q];
            acc[2*q]   += bf2f(u & 0xFFFFu);
            acc[2*q+1] += bf2f(u >> 16);
        }
    }
    float inn = in_norm[node];
    uint* po = (uint*)(out + (size_t)node * D + off);
#pragma unroll
    for (int q = 0; q < NU; ++q) {
        uint lo = f2bf(acc[2*q] * inn);
        uint hi = f2bf(acc[2*q+1] * inn);
        po[q] = lo | (hi << 16);
    }
}

// MFMA GEMM: C[M,256] = A[M,K](bf16) @ W + bias. WT[256][K] bf16, no LDS staging.
// MODE 0: out bf16 = relu(acc+bias)*scale[row]     (h1s, pre-scaled for next gather)
// MODE 1: out bf16 = acc+bias, fused row-L2-norm accumulation into norm_sum
template<int K, int MODE>
__global__ __launch_bounds__(256) void gemm_mfma_kernel(const ushort* __restrict__ A,
                                                        const ushort* __restrict__ WT,
                                                        const float* __restrict__ bias,
                                                        ushort* __restrict__ Cout,
                                                        const float* __restrict__ scale,
                                                        float* __restrict__ norm_sum,
                                                        int M) {
    __shared__ float rowsq[4][64];
    int lane = threadIdx.x & 63, wave = threadIdx.x >> 6;
    int m0 = blockIdx.x * 64, n0 = wave * 64;
    int ll = lane & 15, lh = lane >> 4;
    f32x4 acc[4][4] = {};
    const ushort* Ab = A  + (size_t)(m0 + ll) * K + lh * 8;
    const ushort* Bb = WT + (size_t)(n0 + ll) * K + lh * 8;
#pragma unroll
    for (int k0 = 0; k0 < K; k0 += 32) {
        short8 a[4], b[4];
#pragma unroll
        for (int mi = 0; mi < 4; ++mi) a[mi] = *(const short8*)(Ab + (size_t)mi * 16 * K + k0);
#pragma unroll
        for (int ni = 0; ni < 4; ++ni) b[ni] = *(const short8*)(Bb + (size_t)ni * 16 * K + k0);
#pragma unroll
        for (int mi = 0; mi < 4; ++mi)
#pragma unroll
            for (int ni = 0; ni < 4; ++ni)
                acc[mi][ni] = __builtin_amdgcn_mfma_f32_16x16x32_bf16(a[mi], b[ni], acc[mi][ni], 0, 0, 0);
    }
#pragma unroll
    for (int mi = 0; mi < 4; ++mi) {
#pragma unroll
        for (int r = 0; r < 4; ++r) {
            int row = m0 + mi * 16 + lh * 4 + r;
            float sc = (MODE == 0 && row < M) ? scale[row] : 1.0f;
            float p = 0.0f;
#pragma unroll
            for (int ni = 0; ni < 4; ++ni) {
                int col = n0 + ni * 16 + ll;
                float v = acc[mi][ni][r] + bias[col];
                if (MODE == 0) v = fmaxf(v, 0.0f) * sc;
                else p += v * v;
                if (row < M) Cout[(size_t)row * DIM + col] = f2bf(v);
            }
            if (MODE == 1) {
#pragma unroll
                for (int m = 1; m < 16; m <<= 1) p += __shfl_xor(p, m);
                if (ll == 0) rowsq[wave][mi * 16 + lh * 4 + r] = p;
            }
        }
    }
    if (MODE == 1) {
        __syncthreads();
        if (threadIdx.x < 64) {
            int lr = threadIdx.x;
            float s = rowsq[0][lr] + rowsq[1][lr] + rowsq[2][lr] + rowsq[3][lr];
            float l = (m0 + lr < M) ? sqrtf(s) : 0.0f;
#pragma unroll
            for (int m = 32; m > 0; m >>= 1) l += __shfl_down(l, m);
            if (lr == 0) atomicAdd(norm_sum, l);
        }
    }
}

// One block per graph (n2g is sorted): binary-search node range, no atomics,
// factor computed inline. Writes every output element exactly once.
__global__ __launch_bounds__(256) void pool_kernel(const ushort* __restrict__ h2,
                                                   const int* __restrict__ n2g,
                                                   const float* __restrict__ norm_sum,
                                                   float* __restrict__ out) {
    int g = blockIdx.x, f = threadIdx.x;
    int lo = 0, hi = NODES;
    while (lo < hi) { int mid = (lo + hi) >> 1; if (n2g[mid] < g) lo = mid + 1; else hi = mid; }
    int start = lo;
    hi = NODES;
    while (lo < hi) { int mid = (lo + hi) >> 1; if (n2g[mid] < g + 1) lo = mid + 1; else hi = mid; }
    int end = lo;
    float acc = 0.0f;
    int i = start;
    for (; i + 3 < end; i += 4) {
        acc += (bf2f((uint)h2[(size_t)(i + 0) * DIM + f]) + bf2f((uint)h2[(size_t)(i + 1) * DIM + f]))
             + (bf2f((uint)h2[(size_t)(i + 2) * DIM + f]) + bf2f((uint)h2[(size_t)(i + 3) * DIM + f]));
    }
    for (; i < end; ++i) acc += bf2f((uint)h2[(size_t)i * DIM + f]);
    float factor = 16.0f * (float)NODES / *norm_sum;   // sqrt(256) / mean row norm
    out[(size_t)g * DIM + f] = acc * factor;
}

extern "C" void kernel_launch(void* const* d_in, const int* in_sizes, int n_in,
                              void* d_out, int out_size, void* d_ws, size_t ws_size,
                              hipStream_t stream) {
    const float* x  = (const float*)d_in[0];
    const float* W1 = (const float*)d_in[1];
    const float* b1 = (const float*)d_in[2];
    const float* W2 = (const float*)d_in[3];
    const float* b2 = (const float*)d_in[4];
    const int* src = (const int*)d_in[5];
    const int* dst = (const int*)d_in[6];
    const int* n2g = (const int*)d_in[7];
    float* out = (float*)d_out;

    char* ws = (char*)d_ws;
    size_t off = 0;
    auto alloc = [&](size_t bytes) {
        char* p = ws + off;
        off = (off + bytes + 255) & ~(size_t)255;
        return p;
    };
    uint* histIn    = (uint*)alloc((size_t)HBLOCKS * 2 * HALF_W * 4);  // 25.6 MB
    uint* histOut   = (uint*)alloc((size_t)HBLOCKS * 2 * HALF_W * 4);  // 25.6 MB
    int* deg_in     = (int*)alloc(NODES * 4);
    float* out_norm = (float*)alloc(NODES * 4);
    float* in_norm  = (float*)alloc(NODES * 4);
    int* row_start  = (int*)alloc((NODES + 1) * 4);
    int* src_sorted = (int*)alloc(EDGES * 4);
    int* block_sums = (int*)alloc(SCAN_BLOCKS * 4);
    float* norm_sum = (float*)alloc(4);
    ushort* W1T     = (ushort*)alloc((size_t)DIM * FIN * 2);   // [256][128]
    ushort* W2T     = (ushort*)alloc((size_t)DIM * DIM * 2);   // [256][256]
    // Aliased feature regions:
    // P0: xs [PAD_M][128] bf16 -> low half of A2 | P1: A1 [PAD_M][128] -> high half of A2
    // H : h1s [PAD_M][256] bf16 -> reused as h2 (agg2 consumed h1s before gemm2 writes)
    ushort* xs  = (ushort*)alloc((size_t)PAD_M * FIN * 2);
    ushort* A1  = (ushort*)alloc((size_t)PAD_M * FIN * 2);
    ushort* h1s = (ushort*)alloc((size_t)PAD_M * DIM * 2);
    ushort* A2 = xs;          // [PAD_M][256] bf16, overlays P0+P1
    ushort* h2 = h1s;         // [PAD_M][256] bf16, overlays H

    // CSR build: LDS histograms, zero global atomics anywhere in the pipeline.
    hist_kernel<<<HBLOCKS, 256, 0, stream>>>(dst, histIn);
    hist_kernel<<<HBLOCKS, 256, 0, stream>>>(src, histOut);
    reduce_hist_kernel<<<(2 * HALF_W + 255) / 256, 256, 0, stream>>>(histIn, histOut,
                                                                     deg_in, in_norm, out_norm);
    scan_partials<<<SCAN_BLOCKS, 256, 0, stream>>>(deg_in, block_sums, NODES);
    scan_blocksums<<<1, 256, 0, stream>>>(block_sums, row_start, norm_sum, SCAN_BLOCKS, NODES);
    scan_final<<<SCAN_BLOCKS, 256, 0, stream>>>(deg_in, block_sums, row_start, NODES);
    scatter_lds_kernel<<<HBLOCKS, 256, 0, stream>>>(src, dst, histIn, row_start, src_sorted);

    prep_kernel<<<PRESCALE_BLOCKS + FIN * DIM / 256 + DIM * DIM / 256, 256, 0, stream>>>(
        x, out_norm, xs, W1, W1T, W2, W2T);

    // Layer 1
    agg_kernel<FIN><<<(NODES + 3) / 4, 256, 0, stream>>>(xs, row_start, src_sorted, in_norm, A1);
    gemm_mfma_kernel<FIN, 0><<<PAD_M / 64, 256, 0, stream>>>(A1, W1T, b1, h1s, out_norm, norm_sum, NODES);

    // Layer 2 (gemm2 fuses row-norm accumulation, writes bf16 h2)
    agg_kernel<DIM><<<(NODES + 3) / 4, 256, 0, stream>>>(h1s, row_start, src_sorted, in_norm, A2);
    gemm_mfma_kernel<DIM, 1><<<PAD_M / 64, 256, 0, stream>>>(A2, W2T, b2, h2, nullptr, norm_sum, NODES);

    // Per-graph sum-pool with inline factor; covers all graphs, no memset needed.
    pool_kernel<<<GRAPHS, 256, 0, stream>>>(h2, n2g, norm_sum, out);
}

// Round 8
// 281.746 us; speedup vs baseline: 4.7042x; 1.0352x over previous
//
#include <hip/hip_runtime.h>

#define NODES 50000
#define EDGES 800000
#define FIN 128
#define DIM 256
#define GRAPHS 256
#define PAD_M 50048   // 782 * 64
#define SCAN_BLOCKS ((NODES + 255) / 256)       // 196
#define PRESCALE_BLOCKS (NODES * FIN / 4 / 256) // 6250 exact
#define HBLOCKS 256                             // histogram copies / edge chunks
#define CHUNK (EDGES / HBLOCKS)                 // 3125 edges per block, exact
#define HALF_N 25000                            // nodes per LDS half
#define HALF_W 12500                            // u32 words per half (2 nodes/u32)

typedef short short8 __attribute__((ext_vector_type(8)));
typedef float f32x4 __attribute__((ext_vector_type(4)));

__device__ __forceinline__ float bf2f(uint u) { return __uint_as_float(u << 16); }
__device__ __forceinline__ ushort f2bf(float f) {
    uint b = __float_as_uint(f);
    return (ushort)((b + 0x7FFF + ((b >> 16) & 1)) >> 16);
}

// Per-block LDS histogram of idx[] over its 3125-edge chunk, u16-packed
// (2 nodes per u32; per-block count <= 3125 so no overflow), node range in
// 2 halves of 25000 (50KB LDS each). Dump = streaming writes, NO global atomics.
__global__ __launch_bounds__(256) void hist_kernel(const int* __restrict__ idx,
                                                   uint* __restrict__ histG) {
    __shared__ uint cur[HALF_W];
    int b = blockIdx.x, tid = threadIdx.x;
    int base = b * CHUNK;
    for (int half = 0; half < 2; ++half) {
        for (int j = tid; j < HALF_W; j += 256) cur[j] = 0;
        __syncthreads();
        int lo = half * HALF_N;
        for (int e = base + tid; e < base + CHUNK; e += 256) {
            int local = idx[e] - lo;
            if ((unsigned)local < (unsigned)HALF_N)
                atomicAdd(&cur[local >> 1], 1u << ((local & 1) * 16));
        }
        __syncthreads();
        uint* dstp = histG + (size_t)b * (2 * HALF_W) + half * HALF_W;
        for (int j = tid; j < HALF_W; j += 256) dstp[j] = cur[j];
        __syncthreads();
    }
}

// Sum the 256 copies -> deg_in / norms; in-place transform histIn into
// per-block EXCLUSIVE prefixes (packed u16) = scatter cursor bases.
// histOut is only summed (out_norm).
__global__ __launch_bounds__(256) void reduce_hist_kernel(uint* __restrict__ histIn,
                                                          const uint* __restrict__ histOut,
                                                          int* __restrict__ deg_in,
                                                          float* __restrict__ in_norm,
                                                          float* __restrict__ out_norm) {
    int t32 = blockIdx.x * 256 + threadIdx.x;
    if (t32 >= 2 * HALF_W) return;
    uint lo = 0, hi = 0;
#pragma unroll 4
    for (int c = 0; c < HBLOCKS; ++c) {
        size_t a = (size_t)c * (2 * HALF_W) + t32;
        uint u = histIn[a];
        histIn[a] = lo | (hi << 16);       // exclusive prefix over blocks (fits u16: <= deg)
        lo += u & 0xFFFFu;
        hi += u >> 16;
    }
    uint olo = 0, ohi = 0;
#pragma unroll 4
    for (int c = 0; c < HBLOCKS; ++c) {
        uint u = histOut[(size_t)c * (2 * HALF_W) + t32];
        olo += u & 0xFFFFu;
        ohi += u >> 16;
    }
    int n0 = (t32 < HALF_W) ? 2 * t32 : HALF_N + 2 * (t32 - HALF_W);
    deg_in[n0]     = (int)lo;
    deg_in[n0 + 1] = (int)hi;
    in_norm[n0]      = rsqrtf(fmaxf((float)lo, 1.0f));
    in_norm[n0 + 1]  = rsqrtf(fmaxf((float)hi, 1.0f));
    out_norm[n0]     = rsqrtf(fmaxf((float)olo, 1.0f));
    out_norm[n0 + 1] = rsqrtf(fmaxf((float)ohi, 1.0f));
}

// Phase 1 of row_start scan: per-256-node block sums.
__global__ __launch_bounds__(256) void scan_partials(const int* __restrict__ deg_in,
                                                     int* __restrict__ block_sums, int n) {
    __shared__ int red[4];
    int i = blockIdx.x * 256 + threadIdx.x;
    int v = (i < n) ? deg_in[i] : 0;
    int wave = threadIdx.x >> 6, lane = threadIdx.x & 63;
#pragma unroll
    for (int off = 32; off > 0; off >>= 1) v += __shfl_down(v, off);
    if (lane == 0) red[wave] = v;
    __syncthreads();
    if (threadIdx.x == 0) block_sums[blockIdx.x] = red[0] + red[1] + red[2] + red[3];
}

// Phase 2: scan the block sums (nb <= 256); also zero norm_sum for this launch.
__global__ __launch_bounds__(256) void scan_blocksums(int* __restrict__ block_sums,
                                                      int* __restrict__ row_start,
                                                      float* __restrict__ norm_sum, int nb, int n) {
    __shared__ int s[256];
    int t = threadIdx.x;
    if (t == 0) *norm_sum = 0.0f;
    int v = (t < nb) ? block_sums[t] : 0;
    s[t] = v;
    __syncthreads();
#pragma unroll
    for (int off = 1; off < 256; off <<= 1) {
        int u = (t >= off) ? s[t - off] : 0;
        __syncthreads();
        s[t] += u;
        __syncthreads();
    }
    if (t < nb) block_sums[t] = s[t] - v;          // exclusive prefix
    if (t == nb - 1) row_start[n] = s[t];          // total
}

// Phase 3: intra-block exclusive scan + block offset -> row_start.
__global__ __launch_bounds__(256) void scan_final(const int* __restrict__ deg,
                                                  const int* __restrict__ block_sums,
                                                  int* __restrict__ row_start, int n) {
    __shared__ int s[256];
    int t = threadIdx.x;
    int i = blockIdx.x * 256 + t;
    int v = (i < n) ? deg[i] : 0;
    s[t] = v;
    __syncthreads();
#pragma unroll
    for (int off = 1; off < 256; off <<= 1) {
        int u = (t >= off) ? s[t - off] : 0;
        __syncthreads();
        s[t] += u;
        __syncthreads();
    }
    if (i < n) row_start[i] = block_sums[blockIdx.x] + s[t] - v;
}

// Scatter with LDS cursors seeded from the per-block exclusive prefixes.
// Each block owns disjoint, exact slot ranges per dst node -> no global atomics.
__global__ __launch_bounds__(256) void scatter_lds_kernel(const int* __restrict__ src,
                                                          const int* __restrict__ dst,
                                                          const uint* __restrict__ histIn,
                                                          const int* __restrict__ row_start,
                                                          int* __restrict__ src_sorted) {
    __shared__ uint cur[HALF_W];
    int b = blockIdx.x, tid = threadIdx.x;
    int base = b * CHUNK;
    for (int half = 0; half < 2; ++half) {
        const uint* offp = histIn + (size_t)b * (2 * HALF_W) + half * HALF_W;
        for (int j = tid; j < HALF_W; j += 256) cur[j] = offp[j];
        __syncthreads();
        int lo = half * HALF_N;
        for (int e = base + tid; e < base + CHUNK; e += 256) {
            int d = dst[e];
            int local = d - lo;
            if ((unsigned)local < (unsigned)HALF_N) {
                int sel = (local & 1) * 16;
                uint old = atomicAdd(&cur[local >> 1], 1u << sel);
                int pos = row_start[d] + (int)((old >> sel) & 0xFFFFu);
                src_sorted[pos] = src[e];
            }
        }
        __syncthreads();
    }
}

// Fused: xs = bf16(x * out_norm[row]) | W1T = bf16(W1^T) | W2T = bf16(W2^T).
__global__ __launch_bounds__(256) void prep_kernel(const float* __restrict__ x,
                                                   const float* __restrict__ out_norm,
                                                   ushort* __restrict__ xs,
                                                   const float* __restrict__ W1,
                                                   ushort* __restrict__ W1T,
                                                   const float* __restrict__ W2,
                                                   ushort* __restrict__ W2T) {
    int b = blockIdx.x;
    if (b < PRESCALE_BLOCKS) {
        int t = b * 256 + threadIdx.x;            // < NODES*FIN/4
        int row = t >> 5;                         // FIN/4 = 32 float4 per row
        float on = out_norm[row];
        float4 v = ((const float4*)x)[t];
        ushort4 o;
        o.x = f2bf(v.x * on); o.y = f2bf(v.y * on);
        o.z = f2bf(v.z * on); o.w = f2bf(v.w * on);
        ((ushort4*)xs)[t] = o;
    } else if (b < PRESCALE_BLOCKS + FIN * DIM / 256) {
        int t = (b - PRESCALE_BLOCKS) * 256 + threadIdx.x;   // < 32768
        int n = t >> 7, k = t & 127;
        W1T[t] = f2bf(W1[(size_t)k * DIM + n]);
    } else {
        int t = (b - PRESCALE_BLOCKS - FIN * DIM / 256) * 256 + threadIdx.x;  // < 65536
        int n = t >> 8, k = t & 255;
        W2T[t] = f2bf(W2[(size_t)k * DIM + n]);
    }
}

// Gather-sum aggregation, bf16 in/out, fp32 accumulate. One wave per node.
// 8-edge unroll with branchless masked tail: indices clamped to e1-1 (always
// valid loads), out-of-range edge values cndmask'd to 0. 8*NU dwords in
// flight per lane -> 2x the MLP of the old 4-edge version (latency-bound).
template<int D>
__global__ __launch_bounds__(256) void agg_kernel(const ushort* __restrict__ in,
                                                  const int* __restrict__ row_start,
                                                  const int* __restrict__ src_sorted,
                                                  const float* __restrict__ in_norm,
                                                  ushort* __restrict__ out) {
    constexpr int VPL = D / 64;       // bf16 per lane (2 or 4)
    constexpr int NU = VPL / 2;       // uint loads per lane
    int wave = threadIdx.x >> 6, lane = threadIdx.x & 63;
    int node = blockIdx.x * 4 + wave;
    if (node >= NODES) return;
    int off = lane * VPL;
    int e0 = row_start[node], e1 = row_start[node + 1];
    float acc[VPL] = {};
    int niter = (e1 - e0 + 7) >> 3;
    for (int it = 0; it < niter; ++it) {
        int eb = e0 + it * 8;
        int idx[8];
#pragma unroll
        for (int j = 0; j < 8; ++j) idx[j] = src_sorted[min(eb + j, e1 - 1)];
        uint u[8][NU];
#pragma unroll
        for (int j = 0; j < 8; ++j) {
            const uint* p = (const uint*)(in + (size_t)idx[j] * D + off);
#pragma unroll
            for (int q = 0; q < NU; ++q) u[j][q] = p[q];
        }
#pragma unroll
        for (int j = 0; j < 8; ++j) {
            uint ok = (eb + j < e1) ? 0xFFFFFFFFu : 0u;
#pragma unroll
            for (int q = 0; q < NU; ++q) {
                uint uu = u[j][q] & ok;
                acc[2*q]   += bf2f(uu & 0xFFFFu);
                acc[2*q+1] += bf2f(uu >> 16);
            }
        }
    }
    float inn = in_norm[node];
    uint* po = (uint*)(out + (size_t)node * D + off);
#pragma unroll
    for (int q = 0; q < NU; ++q) {
        uint lo = f2bf(acc[2*q] * inn);
        uint hi = f2bf(acc[2*q+1] * inn);
        po[q] = lo | (hi << 16);
    }
}

// MFMA GEMM: C[M,256] = A[M,K](bf16) @ W + bias. WT[256][K] bf16, no LDS staging.
// MODE 0: out bf16 = relu(acc+bias)*scale[row]     (h1s, pre-scaled for next gather)
// MODE 1: out bf16 = acc+bias, fused row-L2-norm accumulation into norm_sum
template<int K, int MODE>
__global__ __launch_bounds__(256) void gemm_mfma_kernel(const ushort* __restrict__ A,
                                                        const ushort* __restrict__ WT,
                                                        const float* __restrict__ bias,
                                                        ushort* __restrict__ Cout,
                                                        const float* __restrict__ scale,
                                                        float* __restrict__ norm_sum,
                                                        int M) {
    __shared__ float rowsq[4][64];
    int lane = threadIdx.x & 63, wave = threadIdx.x >> 6;
    int m0 = blockIdx.x * 64, n0 = wave * 64;
    int ll = lane & 15, lh = lane >> 4;
    f32x4 acc[4][4] = {};
    const ushort* Ab = A  + (size_t)(m0 + ll) * K + lh * 8;
    const ushort* Bb = WT + (size_t)(n0 + ll) * K + lh * 8;
#pragma unroll
    for (int k0 = 0; k0 < K; k0 += 32) {
        short8 a[4], b[4];
#pragma unroll
        for (int mi = 0; mi < 4; ++mi) a[mi] = *(const short8*)(Ab + (size_t)mi * 16 * K + k0);
#pragma unroll
        for (int ni = 0; ni < 4; ++ni) b[ni] = *(const short8*)(Bb + (size_t)ni * 16 * K + k0);
#pragma unroll
        for (int mi = 0; mi < 4; ++mi)
#pragma unroll
            for (int ni = 0; ni < 4; ++ni)
                acc[mi][ni] = __builtin_amdgcn_mfma_f32_16x16x32_bf16(a[mi], b[ni], acc[mi][ni], 0, 0, 0);
    }
#pragma unroll
    for (int mi = 0; mi < 4; ++mi) {
#pragma unroll
        for (int r = 0; r < 4; ++r) {
            int row = m0 + mi * 16 + lh * 4 + r;
            float sc = (MODE == 0 && row < M) ? scale[row] : 1.0f;
            float p = 0.0f;
#pragma unroll
            for (int ni = 0; ni < 4; ++ni) {
                int col = n0 + ni * 16 + ll;
                float v = acc[mi][ni][r] + bias[col];
                if (MODE == 0) v = fmaxf(v, 0.0f) * sc;
                else p += v * v;
                if (row < M) Cout[(size_t)row * DIM + col] = f2bf(v);
            }
            if (MODE == 1) {
#pragma unroll
                for (int m = 1; m < 16; m <<= 1) p += __shfl_xor(p, m);
                if (ll == 0) rowsq[wave][mi * 16 + lh * 4 + r] = p;
            }
        }
    }
    if (MODE == 1) {
        __syncthreads();
        if (threadIdx.x < 64) {
            int lr = threadIdx.x;
            float s = rowsq[0][lr] + rowsq[1][lr] + rowsq[2][lr] + rowsq[3][lr];
            float l = (m0 + lr < M) ? sqrtf(s) : 0.0f;
#pragma unroll
            for (int m = 32; m > 0; m >>= 1) l += __shfl_down(l, m);
            if (lr == 0) atomicAdd(norm_sum, l);
        }
    }
}

// One block per graph (n2g is sorted): binary-search node range, no atomics,
// factor computed inline. Writes every output element exactly once.
__global__ __launch_bounds__(256) void pool_kernel(const ushort* __restrict__ h2,
                                                   const int* __restrict__ n2g,
                                                   const float* __restrict__ norm_sum,
                                                   float* __restrict__ out) {
    int g = blockIdx.x, f = threadIdx.x;
    int lo = 0, hi = NODES;
    while (lo < hi) { int mid = (lo + hi) >> 1; if (n2g[mid] < g) lo = mid + 1; else hi = mid; }
    int start = lo;
    hi = NODES;
    while (lo < hi) { int mid = (lo + hi) >> 1; if (n2g[mid] < g + 1) lo = mid + 1; else hi = mid; }
    int end = lo;
    float acc = 0.0f;
    int i = start;
    for (; i + 3 < end; i += 4) {
        acc += (bf2f((uint)h2[(size_t)(i + 0) * DIM + f]) + bf2f((uint)h2[(size_t)(i + 1) * DIM + f]))
             + (bf2f((uint)h2[(size_t)(i + 2) * DIM + f]) + bf2f((uint)h2[(size_t)(i + 3) * DIM + f]));
    }
    for (; i < end; ++i) acc += bf2f((uint)h2[(size_t)i * DIM + f]);
    float factor = 16.0f * (float)NODES / *norm_sum;   // sqrt(256) / mean row norm
    out[(size_t)g * DIM + f] = acc * factor;
}

extern "C" void kernel_launch(void* const* d_in, const int* in_sizes, int n_in,
                              void* d_out, int out_size, void* d_ws, size_t ws_size,
                              hipStream_t stream) {
    const float* x  = (const float*)d_in[0];
    const float* W1 = (const float*)d_in[1];
    const float* b1 = (const float*)d_in[2];
    const float* W2 = (const float*)d_in[3];
    const float* b2 = (const float*)d_in[4];
    const int* src = (const int*)d_in[5];
    const int* dst = (const int*)d_in[6];
    const int* n2g = (const int*)d_in[7];
    float* out = (float*)d_out;

    char* ws = (char*)d_ws;
    size_t off = 0;
    auto alloc = [&](size_t bytes) {
        char* p = ws + off;
        off = (off + bytes + 255) & ~(size_t)255;
        return p;
    };
    uint* histIn    = (uint*)alloc((size_t)HBLOCKS * 2 * HALF_W * 4);  // 25.6 MB
    uint* histOut   = (uint*)alloc((size_t)HBLOCKS * 2 * HALF_W * 4);  // 25.6 MB
    int* deg_in     = (int*)alloc(NODES * 4);
    float* out_norm = (float*)alloc(NODES * 4);
    float* in_norm  = (float*)alloc(NODES * 4);
    int* row_start  = (int*)alloc((NODES + 1) * 4);
    int* src_sorted = (int*)alloc(EDGES * 4);
    int* block_sums = (int*)alloc(SCAN_BLOCKS * 4);
    float* norm_sum = (float*)alloc(4);
    ushort* W1T     = (ushort*)alloc((size_t)DIM * FIN * 2);   // [256][128]
    ushort* W2T     = (ushort*)alloc((size_t)DIM * DIM * 2);   // [256][256]
    // Aliased feature regions:
    // P0: xs [PAD_M][128] bf16 -> low half of A2 | P1: A1 [PAD_M][128] -> high half of A2
    // H : h1s [PAD_M][256] bf16 -> reused as h2 (agg2 consumed h1s before gemm2 writes)
    ushort* xs  = (ushort*)alloc((size_t)PAD_M * FIN * 2);
    ushort* A1  = (ushort*)alloc((size_t)PAD_M * FIN * 2);
    ushort* h1s = (ushort*)alloc((size_t)PAD_M * DIM * 2);
    ushort* A2 = xs;          // [PAD_M][256] bf16, overlays P0+P1
    ushort* h2 = h1s;         // [PAD_M][256] bf16, overlays H

    // CSR build: LDS histograms, zero global atomics anywhere in the pipeline.
    hist_kernel<<<HBLOCKS, 256, 0, stream>>>(dst, histIn);
    hist_kernel<<<HBLOCKS, 256, 0, stream>>>(src, histOut);
    reduce_hist_kernel<<<(2 * HALF_W + 255) / 256, 256, 0, stream>>>(histIn, histOut,
                                                                     deg_in, in_norm, out_norm);
    scan_partials<<<SCAN_BLOCKS, 256, 0, stream>>>(deg_in, block_sums, NODES);
    scan_blocksums<<<1, 256, 0, stream>>>(block_sums, row_start, norm_sum, SCAN_BLOCKS, NODES);
    scan_final<<<SCAN_BLOCKS, 256, 0, stream>>>(deg_in, block_sums, row_start, NODES);
    scatter_lds_kernel<<<HBLOCKS, 256, 0, stream>>>(src, dst, histIn, row_start, src_sorted);

    prep_kernel<<<PRESCALE_BLOCKS + FIN * DIM / 256 + DIM * DIM / 256, 256, 0, stream>>>(
        x, out_norm, xs, W1, W1T, W2, W2T);

    // Layer 1
    agg_kernel<FIN><<<(NODES + 3) / 4, 256, 0, stream>>>(xs, row_start, src_sorted, in_norm, A1);
    gemm_mfma_kernel<FIN, 0><<<PAD_M / 64, 256, 0, stream>>>(A1, W1T, b1, h1s, out_norm, norm_sum, NODES);

    // Layer 2 (gemm2 fuses row-norm accumulation, writes bf16 h2)
    agg_kernel<DIM><<<(NODES + 3) / 4, 256, 0, stream>>>(h1s, row_start, src_sorted, in_norm, A2);
    gemm_mfma_kernel<DIM, 1><<<PAD_M / 64, 256, 0, stream>>>(A2, W2T, b2, h2, nullptr, norm_sum, NODES);

    // Per-graph sum-pool with inline factor; covers all graphs, no memset needed.
    pool_kernel<<<GRAPHS, 256, 0, stream>>>(h2, n2g, norm_sum, out);
}